// Round 3
// baseline (1539.580 us; speedup 1.0000x reference)
//
#include <hip/hip_runtime.h>

#define FDIM   64
#define BSHIFT 9            // 512 nodes per bucket
#define BNODES 512
#define BCAP   10240        // slots per bucket (mean 8192, sd ~90)
#define EPB    8192         // edges per k_bucket block

// ---------------- pass A: bucket edges by dst, pack (localDst<<17 | src) ----------------
__global__ __launch_bounds__(256) void k_bucket(const int* __restrict__ src,
                                                const int* __restrict__ dst,
                                                int* __restrict__ gCursor,
                                                unsigned* __restrict__ pairs,
                                                int E, int N) {
    __shared__ int cnt[256];
    __shared__ int base[256];
    __shared__ int cur[256];
    const int t  = threadIdx.x;
    const int e0 = blockIdx.x * EPB;
    cnt[t] = 0; cur[t] = 0;
    __syncthreads();

    // phase 1: count buckets
    #pragma unroll 4
    for (int i = 0; i < EPB / 256; ++i) {
        int e = e0 + i * 256 + t;
        if (e < E) {
            int d = dst[e];
            d = min(max(d, 0), N - 1);
            atomicAdd(&cnt[d >> BSHIFT], 1);
        }
    }
    __syncthreads();
    // phase 2: reserve global ranges
    if (cnt[t] > 0) base[t] = atomicAdd(&gCursor[t], cnt[t]);
    __syncthreads();
    // phase 3: write packed pairs
    #pragma unroll 4
    for (int i = 0; i < EPB / 256; ++i) {
        int e = e0 + i * 256 + t;
        if (e < E) {
            int d = dst[e], s = src[e];
            d = min(max(d, 0), N - 1);
            s = min(max(s, 0), N - 1);
            int b = d >> BSHIFT;
            int slot = base[b] + atomicAdd(&cur[b], 1);
            if (slot < BCAP)
                pairs[(size_t)b * BCAP + slot] =
                    ((unsigned)(d & (BNODES - 1)) << 17) | (unsigned)s;
        }
    }
}

// ---------------- per-bucket degree histogram -> dinv = rsqrt(deg+1) ----------------
__global__ __launch_bounds__(256) void k_deg_dinv(const unsigned* __restrict__ pairs,
                                                  const int* __restrict__ gCursor,
                                                  float* __restrict__ dinv, int N) {
    __shared__ int cnt[BNODES];
    const int b = blockIdx.x, t = threadIdx.x;
    cnt[t] = 0; cnt[t + 256] = 0;
    __syncthreads();
    const int count = min(gCursor[b], BCAP);
    const unsigned* p = pairs + (size_t)b * BCAP;
    for (int i = t; i < count; i += 256)
        atomicAdd(&cnt[p[i] >> 17], 1);
    __syncthreads();
    const int n0 = b << BSHIFT;
    #pragma unroll
    for (int i = 0; i < 2; ++i) {
        int li = t + i * 256;
        int n = n0 + li;
        if (n < N) dinv[n] = rsqrtf((float)(cnt[li] + 1));
    }
}

// ---------------- dense GEMM with row scale: O[r] = dinv[r] * (X @ W)[r] ----------------
__global__ __launch_bounds__(256) void k_gemm64s(const float* __restrict__ X,
                                                 const float* __restrict__ W,
                                                 const float* __restrict__ dinv,
                                                 float* __restrict__ O, int N) {
    __shared__ float Xs[64][FDIM];
    __shared__ float Ws[64][FDIM];
    const int tid  = threadIdx.x;
    const int base = blockIdx.x * 64;

    #pragma unroll
    for (int i = 0; i < 4; ++i) {
        int idx = tid + i * 256;
        reinterpret_cast<float4*>(&Ws[0][0])[idx] =
            reinterpret_cast<const float4*>(W)[idx];
    }
    #pragma unroll
    for (int i = 0; i < 4; ++i) {
        int idx = tid + i * 256;
        int r = idx >> 4;
        int gr = base + r;
        float4 v = make_float4(0.f, 0.f, 0.f, 0.f);
        if (gr < N) v = reinterpret_cast<const float4*>(X)[(size_t)gr * 16 + (idx & 15)];
        reinterpret_cast<float4*>(&Xs[0][0])[idx] = v;
    }
    __syncthreads();

    const int c  = tid & 63;
    const int rq = tid >> 6;
    float acc[16];
    #pragma unroll
    for (int j = 0; j < 16; ++j) acc[j] = 0.f;

    #pragma unroll 8
    for (int k = 0; k < 64; ++k) {
        float wv = Ws[k][c];
        #pragma unroll
        for (int j = 0; j < 16; ++j)
            acc[j] = fmaf(Xs[rq * 16 + j][k], wv, acc[j]);
    }

    #pragma unroll
    for (int j = 0; j < 16; ++j) {
        int gr = base + rq * 16 + j;
        if (gr < N) O[(size_t)gr * FDIM + c] = acc[j] * dinv[gr];
    }
}

// ---------------- per-bucket aggregate in LDS + fused epilogue ----------------
// acc[localDst] += Hs[src]  (Hs pre-scaled by dinv[src])
// out[n] = relu?( dinv[n] * (acc[n] + Hs[n]) + b )
__global__ __launch_bounds__(1024) void k_agg(const float* __restrict__ Hs,
                                              const unsigned* __restrict__ pairs,
                                              const int* __restrict__ gCursor,
                                              const float* __restrict__ dinv,
                                              const float* __restrict__ bias,
                                              float* __restrict__ O,
                                              int N, int do_relu) {
    __shared__ float acc[BNODES * FDIM];   // 128 KB
    const int b = blockIdx.x, t = threadIdx.x;
    float4* accv = reinterpret_cast<float4*>(acc);
    #pragma unroll
    for (int i = 0; i < (BNODES * FDIM / 4) / 1024; ++i)
        accv[t + i * 1024] = make_float4(0.f, 0.f, 0.f, 0.f);
    __syncthreads();

    const int count = min(gCursor[b], BCAP);
    const unsigned* p = pairs + (size_t)b * BCAP;
    const int lane = t & 63;
    const int w    = t >> 6;     // 16 waves

    for (int c0 = w * 64; c0 < count; c0 += 16 * 64) {
        int kk = c0 + lane;
        unsigned pk = (kk < count) ? p[kk] : 0u;
        int cnt = min(64, count - c0);
        int j = 0;
        for (; j + 3 < cnt; j += 4) {
            unsigned pk0 = __shfl(pk, j,     64);
            unsigned pk1 = __shfl(pk, j + 1, 64);
            unsigned pk2 = __shfl(pk, j + 2, 64);
            unsigned pk3 = __shfl(pk, j + 3, 64);
            float h0 = Hs[(size_t)(pk0 & 0x1FFFFu) * FDIM + lane];
            float h1 = Hs[(size_t)(pk1 & 0x1FFFFu) * FDIM + lane];
            float h2 = Hs[(size_t)(pk2 & 0x1FFFFu) * FDIM + lane];
            float h3 = Hs[(size_t)(pk3 & 0x1FFFFu) * FDIM + lane];
            atomicAdd(&acc[(pk0 >> 17) * FDIM + lane], h0);
            atomicAdd(&acc[(pk1 >> 17) * FDIM + lane], h1);
            atomicAdd(&acc[(pk2 >> 17) * FDIM + lane], h2);
            atomicAdd(&acc[(pk3 >> 17) * FDIM + lane], h3);
        }
        for (; j < cnt; ++j) {
            unsigned pk0 = __shfl(pk, j, 64);
            float h0 = Hs[(size_t)(pk0 & 0x1FFFFu) * FDIM + lane];
            atomicAdd(&acc[(pk0 >> 17) * FDIM + lane], h0);
        }
    }
    __syncthreads();

    // epilogue: 16 waves cover 512 rows
    const int n0 = b << BSHIFT;
    for (int r = w; r < BNODES; r += 16) {
        int n = n0 + r;
        if (n >= N) continue;
        float di = dinv[n];
        float v = di * (acc[r * FDIM + lane] + Hs[(size_t)n * FDIM + lane]) + bias[lane];
        if (do_relu) v = fmaxf(v, 0.f);
        O[(size_t)n * FDIM + lane] = v;
    }
}

extern "C" void kernel_launch(void* const* d_in, const int* in_sizes, int n_in,
                              void* d_out, int out_size, void* d_ws, size_t ws_size,
                              hipStream_t stream) {
    const float* x  = (const float*)d_in[0];
    const int*   ei = (const int*)  d_in[1];   // [2, E], int32
    const float* W1 = (const float*)d_in[2];
    const float* b1 = (const float*)d_in[3];
    const float* W2 = (const float*)d_in[4];
    const float* b2 = (const float*)d_in[5];
    float* out = (float*)d_out;

    const int N = in_sizes[0] / FDIM;   // 100000
    const int E = in_sizes[1] / 2;      // 1600000
    const int* src = ei;
    const int* dst = ei + E;

    const int nB = (N + BNODES - 1) >> BSHIFT;   // 196

    auto align1k = [](size_t v) { return (v + 1023) & ~(size_t)1023; };
    char* p = (char*)d_ws;
    int*      gCursor = (int*)p;        p += align1k(256 * 4);
    float*    dinv    = (float*)p;      p += align1k((size_t)N * 4);
    unsigned* pairs   = (unsigned*)p;   p += align1k((size_t)nB * BCAP * 4);
    float*    H       = (float*)p;      // N*64 floats (scaled activations)

    // ---- bucket build ----
    hipMemsetAsync(gCursor, 0, 256 * 4, stream);
    k_bucket<<<(E + EPB - 1) / EPB, 256, 0, stream>>>(src, dst, gCursor, pairs, E, N);
    k_deg_dinv<<<nB, 256, 0, stream>>>(pairs, gCursor, dinv, N);

    const int gemmBlocks = (N + 63) / 64;

    // ---- layer 1 ----
    k_gemm64s<<<gemmBlocks, 256, 0, stream>>>(x, W1, dinv, H, N);
    k_agg<<<nB, 1024, 0, stream>>>(H, pairs, gCursor, dinv, b1, out, N, 1);

    // ---- layer 2 ----  (input = layer-1 output living in d_out)
    k_gemm64s<<<gemmBlocks, 256, 0, stream>>>(out, W2, dinv, H, N);
    k_agg<<<nB, 1024, 0, stream>>>(H, pairs, gCursor, dinv, b2, out, N, 0);
}

// Round 4
// 232.600 us; speedup vs baseline: 6.6190x; 6.6190x over previous
//
#include <hip/hip_runtime.h>

#define FDIM   64
#define BSHIFT 9            // 512 nodes per bucket
#define BNODES 512
#define BCAP   8960         // slots per bucket (mean 8163, sd ~90 -> +8.8 sigma)
#define EPB    4096         // edges per k_bucket block

// ---------------- pass A: bucket edges by dst, pack (localDst<<17 | src) ----------------
__global__ __launch_bounds__(256) void k_bucket(const int* __restrict__ src,
                                                const int* __restrict__ dst,
                                                int* __restrict__ gCursor,
                                                unsigned* __restrict__ pairs,
                                                int E, int N) {
    __shared__ int cnt[256];
    __shared__ int base[256];
    __shared__ int cur[256];
    const int t  = threadIdx.x;
    const int e0 = blockIdx.x * EPB;
    cnt[t] = 0; cur[t] = 0;
    __syncthreads();

    // phase 1: count buckets
    #pragma unroll 4
    for (int i = 0; i < EPB / 256; ++i) {
        int e = e0 + i * 256 + t;
        if (e < E) {
            int d = dst[e];
            d = min(max(d, 0), N - 1);
            atomicAdd(&cnt[d >> BSHIFT], 1);
        }
    }
    __syncthreads();
    // phase 2: reserve global ranges
    if (cnt[t] > 0) base[t] = atomicAdd(&gCursor[t], cnt[t]);
    __syncthreads();
    // phase 3: write packed pairs
    #pragma unroll 4
    for (int i = 0; i < EPB / 256; ++i) {
        int e = e0 + i * 256 + t;
        if (e < E) {
            int d = dst[e], s = src[e];
            d = min(max(d, 0), N - 1);
            s = min(max(s, 0), N - 1);
            int b = d >> BSHIFT;
            int slot = base[b] + atomicAdd(&cur[b], 1);
            if (slot < BCAP)
                pairs[(size_t)b * BCAP + slot] =
                    ((unsigned)(d & (BNODES - 1)) << 17) | (unsigned)s;
        }
    }
}

// ---------------- pass B: per-bucket counting sort (in LDS), in-place scatter ----------------
// Produces: pairs[b*BCAP + ...] holds src indices sorted by localDst,
//           beg[n]/endp[n] global slot ranges, dinv[n] = rsqrt(deg+1).
__global__ __launch_bounds__(1024) void k_sort(unsigned* __restrict__ pairs,
                                               const int* __restrict__ gCursor,
                                               float* __restrict__ dinv,
                                               int* __restrict__ beg,
                                               int* __restrict__ endp,
                                               int N) {
    __shared__ unsigned buf[BCAP];     // 35 KB
    __shared__ int cnt[BNODES];
    __shared__ int scn[BNODES];
    __shared__ int cur[BNODES];
    const int b = blockIdx.x, t = threadIdx.x;
    const int count = min(gCursor[b], BCAP);
    unsigned* p = pairs + (size_t)b * BCAP;

    if (t < BNODES) cnt[t] = 0;
    __syncthreads();
    // stage to LDS + histogram
    for (int i = t; i < count; i += 1024) {
        unsigned pk = p[i];
        buf[i] = pk;
        atomicAdd(&cnt[pk >> 17], 1);
    }
    __syncthreads();
    // inclusive scan of cnt (512 entries, Hillis-Steele)
    if (t < BNODES) scn[t] = cnt[t];
    __syncthreads();
    for (int off = 1; off < BNODES; off <<= 1) {
        int v = 0;
        if (t < BNODES && t >= off) v = scn[t - off];
        __syncthreads();
        if (t < BNODES) scn[t] += v;
        __syncthreads();
    }
    // per-node outputs + cursors
    if (t < BNODES) {
        int c  = cnt[t];
        int st = scn[t] - c;        // exclusive
        cur[t] = st;
        int n = (b << BSHIFT) + t;
        if (n < N) {
            beg[n]  = b * BCAP + st;
            endp[n] = b * BCAP + st + c;
            dinv[n] = rsqrtf((float)(c + 1));
        }
    }
    __syncthreads();
    // scatter back (in place is safe: global reads all done, source is LDS)
    for (int i = t; i < count; i += 1024) {
        unsigned pk = buf[i];
        int pos = atomicAdd(&cur[pk >> 17], 1);
        p[pos] = pk & 0x1FFFFu;     // store src only
    }
}

// ---------------- dense GEMM with row scale: O[r] = dinv[r] * (X @ W)[r] ----------------
__global__ __launch_bounds__(256) void k_gemm64s(const float* __restrict__ X,
                                                 const float* __restrict__ W,
                                                 const float* __restrict__ dinv,
                                                 float* __restrict__ O, int N) {
    __shared__ float Xs[64][FDIM];
    __shared__ float Ws[64][FDIM];
    const int tid  = threadIdx.x;
    const int base = blockIdx.x * 64;

    #pragma unroll
    for (int i = 0; i < 4; ++i) {
        int idx = tid + i * 256;
        reinterpret_cast<float4*>(&Ws[0][0])[idx] =
            reinterpret_cast<const float4*>(W)[idx];
    }
    #pragma unroll
    for (int i = 0; i < 4; ++i) {
        int idx = tid + i * 256;
        int r = idx >> 4;
        int gr = base + r;
        float4 v = make_float4(0.f, 0.f, 0.f, 0.f);
        if (gr < N) v = reinterpret_cast<const float4*>(X)[(size_t)gr * 16 + (idx & 15)];
        reinterpret_cast<float4*>(&Xs[0][0])[idx] = v;
    }
    __syncthreads();

    const int c  = tid & 63;
    const int rq = tid >> 6;
    float acc[16];
    #pragma unroll
    for (int j = 0; j < 16; ++j) acc[j] = 0.f;

    #pragma unroll 8
    for (int k = 0; k < 64; ++k) {
        float wv = Ws[k][c];
        #pragma unroll
        for (int j = 0; j < 16; ++j)
            acc[j] = fmaf(Xs[rq * 16 + j][k], wv, acc[j]);
    }

    #pragma unroll
    for (int j = 0; j < 16; ++j) {
        int gr = base + rq * 16 + j;
        if (gr < N) O[(size_t)gr * FDIM + c] = acc[j] * dinv[gr];
    }
}

// ---------------- CSR gather-aggregate, float4 x 4-edge groups, fused epilogue ----------------
// one wave per node; 4 groups of 16 lanes, each group gathers one edge row as float4.
// out[n] = relu?( dinv[n] * (sum_s Hs[s] + Hs[n]) + b ),  Hs pre-scaled by dinv.
__global__ __launch_bounds__(256) void k_agg(const float* __restrict__ Hs,
                                             const int* __restrict__ srcList,
                                             const int* __restrict__ beg,
                                             const int* __restrict__ endp,
                                             const float* __restrict__ dinv,
                                             const float* __restrict__ bias,
                                             float* __restrict__ O,
                                             int N, int do_relu) {
    const int lane = threadIdx.x & 63;
    const int w    = threadIdx.x >> 6;
    const int node = blockIdx.x * 4 + w;
    if (node >= N) return;
    const int g  = lane >> 4;      // edge-slot within quad
    const int c4 = lane & 15;      // float4 chunk of the 64-float row
    const float4* Hv = reinterpret_cast<const float4*>(Hs);

    const int kb = beg[node], ke = endp[node];
    float4 acc = make_float4(0.f, 0.f, 0.f, 0.f);

    for (int k0 = kb; k0 < ke; k0 += 64) {
        int kk = k0 + lane;
        int s = (kk < ke) ? srcList[kk] : 0;
        int cnt = min(64, ke - k0);
        int nf = cnt >> 2;
        #pragma unroll 4
        for (int j = 0; j < nf; ++j) {
            int sj = __shfl(s, (j << 2) + g, 64);
            float4 h = Hv[(size_t)sj * 16 + c4];
            acc.x += h.x; acc.y += h.y; acc.z += h.z; acc.w += h.w;
        }
        int rem = cnt & 3;
        if (rem) {
            int e = (nf << 2) + g;
            int sj = __shfl(s, min(e, 63), 64);
            if (g < rem) {
                float4 h = Hv[(size_t)sj * 16 + c4];
                acc.x += h.x; acc.y += h.y; acc.z += h.z; acc.w += h.w;
            }
        }
    }

    // reduce the 4 groups (same c4 -> same features)
    acc.x += __shfl_xor(acc.x, 16, 64); acc.y += __shfl_xor(acc.y, 16, 64);
    acc.z += __shfl_xor(acc.z, 16, 64); acc.w += __shfl_xor(acc.w, 16, 64);
    acc.x += __shfl_xor(acc.x, 32, 64); acc.y += __shfl_xor(acc.y, 32, 64);
    acc.z += __shfl_xor(acc.z, 32, 64); acc.w += __shfl_xor(acc.w, 32, 64);

    const float di = dinv[node];
    float4 self = Hv[(size_t)node * 16 + c4];
    float4 bb = reinterpret_cast<const float4*>(bias)[c4];
    float4 r;
    r.x = fmaf(di, acc.x + self.x, bb.x);
    r.y = fmaf(di, acc.y + self.y, bb.y);
    r.z = fmaf(di, acc.z + self.z, bb.z);
    r.w = fmaf(di, acc.w + self.w, bb.w);
    if (do_relu) {
        r.x = fmaxf(r.x, 0.f); r.y = fmaxf(r.y, 0.f);
        r.z = fmaxf(r.z, 0.f); r.w = fmaxf(r.w, 0.f);
    }
    if (lane < 16)
        reinterpret_cast<float4*>(O)[(size_t)node * 16 + c4] = r;
}

extern "C" void kernel_launch(void* const* d_in, const int* in_sizes, int n_in,
                              void* d_out, int out_size, void* d_ws, size_t ws_size,
                              hipStream_t stream) {
    const float* x  = (const float*)d_in[0];
    const int*   ei = (const int*)  d_in[1];   // [2, E], int32
    const float* W1 = (const float*)d_in[2];
    const float* b1 = (const float*)d_in[3];
    const float* W2 = (const float*)d_in[4];
    const float* b2 = (const float*)d_in[5];
    float* out = (float*)d_out;

    const int N = in_sizes[0] / FDIM;   // 100000
    const int E = in_sizes[1] / 2;      // 1600000
    const int* src = ei;
    const int* dst = ei + E;

    const int nB = (N + BNODES - 1) >> BSHIFT;   // 196

    auto align1k = [](size_t v) { return (v + 1023) & ~(size_t)1023; };
    char* p = (char*)d_ws;
    int*      gCursor = (int*)p;        p += align1k(256 * 4);
    float*    dinv    = (float*)p;      p += align1k((size_t)N * 4);
    int*      beg     = (int*)p;        p += align1k((size_t)N * 4);
    int*      endp    = (int*)p;        p += align1k((size_t)N * 4);
    unsigned* pairs   = (unsigned*)p;   p += align1k((size_t)nB * BCAP * 4);
    float*    H       = (float*)p;      // N*64 floats (scaled activations)

    // ---- CSR build via bucket + LDS counting sort ----
    hipMemsetAsync(gCursor, 0, 256 * 4, stream);
    k_bucket<<<(E + EPB - 1) / EPB, 256, 0, stream>>>(src, dst, gCursor, pairs, E, N);
    k_sort<<<nB, 1024, 0, stream>>>(pairs, gCursor, dinv, beg, endp, N);

    const int gemmBlocks = (N + 63) / 64;
    const int aggBlocks  = (N + 3) / 4;
    const int* srcList = (const int*)pairs;

    // ---- layer 1 ----
    k_gemm64s<<<gemmBlocks, 256, 0, stream>>>(x, W1, dinv, H, N);
    k_agg<<<aggBlocks, 256, 0, stream>>>(H, srcList, beg, endp, dinv, b1, out, N, 1);

    // ---- layer 2 ----  (input = layer-1 output living in d_out)
    k_gemm64s<<<gemmBlocks, 256, 0, stream>>>(out, W2, dinv, H, N);
    k_agg<<<aggBlocks, 256, 0, stream>>>(H, srcList, beg, endp, dinv, b2, out, N, 0);
}

// Round 5
// 200.960 us; speedup vs baseline: 7.6611x; 1.1574x over previous
//
#include <hip/hip_runtime.h>

#define FDIM   64
#define BSHIFT 9            // 512 nodes per bucket
#define BNODES 512
#define BCAP   8960         // slots per bucket (mean 8163, sd ~90 -> +8.8 sigma)
#define EPB    4096         // edges per k_bucket block

typedef unsigned short bf16_t;

__device__ __forceinline__ float bflo(unsigned u) { return __uint_as_float(u << 16); }
__device__ __forceinline__ float bfhi(unsigned u) { return __uint_as_float(u & 0xFFFF0000u); }
__device__ __forceinline__ unsigned f2bf(float f) {   // RNE, returns low 16 bits
    unsigned u = __float_as_uint(f);
    u += 0x7FFFu + ((u >> 16) & 1u);
    return u >> 16;
}
__device__ __forceinline__ void addbf8(float* acc, uint4 v) {
    acc[0] += bflo(v.x); acc[1] += bfhi(v.x);
    acc[2] += bflo(v.y); acc[3] += bfhi(v.y);
    acc[4] += bflo(v.z); acc[5] += bfhi(v.z);
    acc[6] += bflo(v.w); acc[7] += bfhi(v.w);
}

// ---------------- pass A: bucket edges by dst, pack (localDst<<17 | src) ----------------
__global__ __launch_bounds__(256) void k_bucket(const int* __restrict__ src,
                                                const int* __restrict__ dst,
                                                int* __restrict__ gCursor,
                                                unsigned* __restrict__ pairs,
                                                int E, int N) {
    __shared__ int cnt[256];
    __shared__ int base[256];
    __shared__ int cur[256];
    const int t  = threadIdx.x;
    const int e0 = blockIdx.x * EPB;
    cnt[t] = 0; cur[t] = 0;
    __syncthreads();

    #pragma unroll 4
    for (int i = 0; i < EPB / 256; ++i) {
        int e = e0 + i * 256 + t;
        if (e < E) {
            int d = dst[e];
            d = min(max(d, 0), N - 1);
            atomicAdd(&cnt[d >> BSHIFT], 1);
        }
    }
    __syncthreads();
    if (cnt[t] > 0) base[t] = atomicAdd(&gCursor[t], cnt[t]);
    __syncthreads();
    #pragma unroll 4
    for (int i = 0; i < EPB / 256; ++i) {
        int e = e0 + i * 256 + t;
        if (e < E) {
            int d = dst[e], s = src[e];
            d = min(max(d, 0), N - 1);
            s = min(max(s, 0), N - 1);
            int b = d >> BSHIFT;
            int slot = base[b] + atomicAdd(&cur[b], 1);
            if (slot < BCAP)
                pairs[(size_t)b * BCAP + slot] =
                    ((unsigned)(d & (BNODES - 1)) << 17) | (unsigned)s;
        }
    }
}

// ---------------- pass B: per-bucket counting sort (in LDS), in-place scatter ----------------
__global__ __launch_bounds__(1024) void k_sort(unsigned* __restrict__ pairs,
                                               const int* __restrict__ gCursor,
                                               float* __restrict__ dinv,
                                               int* __restrict__ beg,
                                               int* __restrict__ endp,
                                               int N) {
    __shared__ unsigned buf[BCAP];     // 35 KB
    __shared__ int cnt[BNODES];
    __shared__ int scn[BNODES];
    __shared__ int cur[BNODES];
    const int b = blockIdx.x, t = threadIdx.x;
    const int count = min(gCursor[b], BCAP);
    unsigned* p = pairs + (size_t)b * BCAP;

    if (t < BNODES) cnt[t] = 0;
    __syncthreads();
    for (int i = t; i < count; i += 1024) {
        unsigned pk = p[i];
        buf[i] = pk;
        atomicAdd(&cnt[pk >> 17], 1);
    }
    __syncthreads();
    if (t < BNODES) scn[t] = cnt[t];
    __syncthreads();
    for (int off = 1; off < BNODES; off <<= 1) {
        int v = 0;
        if (t < BNODES && t >= off) v = scn[t - off];
        __syncthreads();
        if (t < BNODES) scn[t] += v;
        __syncthreads();
    }
    if (t < BNODES) {
        int c  = cnt[t];
        int st = scn[t] - c;
        cur[t] = st;
        int n = (b << BSHIFT) + t;
        if (n < N) {
            beg[n]  = b * BCAP + st;
            endp[n] = b * BCAP + st + c;
            dinv[n] = rsqrtf((float)(c + 1));
        }
    }
    __syncthreads();
    for (int i = t; i < count; i += 1024) {
        unsigned pk = buf[i];
        int pos = atomicAdd(&cur[pk >> 17], 1);
        p[pos] = pk & 0x1FFFFu;
    }
}

// ---------------- GEMM (fp32 in): Ob[r] = bf16( dinv[r] * (X @ W)[r] ) ----------------
__global__ __launch_bounds__(256) void k_gemm_f32(const float* __restrict__ X,
                                                  const float* __restrict__ W,
                                                  const float* __restrict__ dinv,
                                                  bf16_t* __restrict__ Ob, int N) {
    __shared__ float Xs[64][FDIM];
    __shared__ float Ws[64][FDIM];
    const int tid  = threadIdx.x;
    const int base = blockIdx.x * 64;

    #pragma unroll
    for (int i = 0; i < 4; ++i) {
        int idx = tid + i * 256;
        reinterpret_cast<float4*>(&Ws[0][0])[idx] =
            reinterpret_cast<const float4*>(W)[idx];
    }
    #pragma unroll
    for (int i = 0; i < 4; ++i) {
        int idx = tid + i * 256;
        int r = idx >> 4;
        int gr = base + r;
        float4 v = make_float4(0.f, 0.f, 0.f, 0.f);
        if (gr < N) v = reinterpret_cast<const float4*>(X)[(size_t)gr * 16 + (idx & 15)];
        reinterpret_cast<float4*>(&Xs[0][0])[idx] = v;
    }
    __syncthreads();

    const int c  = tid & 63;
    const int rq = tid >> 6;
    float acc[16];
    #pragma unroll
    for (int j = 0; j < 16; ++j) acc[j] = 0.f;

    #pragma unroll 8
    for (int k = 0; k < 64; ++k) {
        float wv = Ws[k][c];
        #pragma unroll
        for (int j = 0; j < 16; ++j)
            acc[j] = fmaf(Xs[rq * 16 + j][k], wv, acc[j]);
    }

    #pragma unroll
    for (int j = 0; j < 16; ++j) {
        int gr = base + rq * 16 + j;
        if (gr < N) Ob[(size_t)gr * FDIM + c] = (bf16_t)f2bf(acc[j] * dinv[gr]);
    }
}

// ---------------- GEMM (bf16 in): Ob[r] = bf16( dinv[r] * (Y @ W)[r] ) ----------------
__global__ __launch_bounds__(256) void k_gemm_bf16(const bf16_t* __restrict__ Y,
                                                   const float* __restrict__ W,
                                                   const float* __restrict__ dinv,
                                                   bf16_t* __restrict__ Ob, int N) {
    __shared__ float Xs[64][FDIM];
    __shared__ float Ws[64][FDIM];
    const int tid  = threadIdx.x;
    const int base = blockIdx.x * 64;

    #pragma unroll
    for (int i = 0; i < 4; ++i) {
        int idx = tid + i * 256;
        reinterpret_cast<float4*>(&Ws[0][0])[idx] =
            reinterpret_cast<const float4*>(W)[idx];
    }
    // stage 64 bf16 rows (8 uint4 per row = 512 uint4 total)
    #pragma unroll
    for (int i = 0; i < 2; ++i) {
        int idx = tid + i * 256;
        int r = idx >> 3, ci = idx & 7;
        int gr = base + r;
        uint4 v = make_uint4(0u, 0u, 0u, 0u);
        if (gr < N) v = reinterpret_cast<const uint4*>(Y)[(size_t)gr * 8 + ci];
        float* xp = &Xs[r][ci * 8];
        xp[0] = bflo(v.x); xp[1] = bfhi(v.x);
        xp[2] = bflo(v.y); xp[3] = bfhi(v.y);
        xp[4] = bflo(v.z); xp[5] = bfhi(v.z);
        xp[6] = bflo(v.w); xp[7] = bfhi(v.w);
    }
    __syncthreads();

    const int c  = tid & 63;
    const int rq = tid >> 6;
    float acc[16];
    #pragma unroll
    for (int j = 0; j < 16; ++j) acc[j] = 0.f;

    #pragma unroll 8
    for (int k = 0; k < 64; ++k) {
        float wv = Ws[k][c];
        #pragma unroll
        for (int j = 0; j < 16; ++j)
            acc[j] = fmaf(Xs[rq * 16 + j][k], wv, acc[j]);
    }

    #pragma unroll
    for (int j = 0; j < 16; ++j) {
        int gr = base + rq * 16 + j;
        if (gr < N) Ob[(size_t)gr * FDIM + c] = (bf16_t)f2bf(acc[j] * dinv[gr]);
    }
}

// ---------------- CSR gather-aggregate (bf16 rows), fused epilogue ----------------
// one wave per node; 8 groups of 8 lanes, each group gathers one 128B bf16 row per step.
// out[n] = relu?( dinv[n] * (sum_s Hs[s] + Hs[n]) + b ),  Hs pre-scaled by dinv.
__global__ __launch_bounds__(256) void k_agg(const bf16_t* __restrict__ Hs,
                                             const int* __restrict__ srcList,
                                             const int* __restrict__ beg,
                                             const int* __restrict__ endp,
                                             const float* __restrict__ dinv,
                                             const float* __restrict__ bias,
                                             float* __restrict__ Of,
                                             bf16_t* __restrict__ Ob,
                                             int N, int do_relu) {
    const int lane = threadIdx.x & 63;
    const int w    = threadIdx.x >> 6;
    const int node = blockIdx.x * 4 + w;
    if (node >= N) return;
    const int g  = lane >> 3;      // edge-slot within octet
    const int c8 = lane & 7;       // uint4 chunk (8 bf16 feats) of the row
    const uint4* Hv = reinterpret_cast<const uint4*>(Hs);

    const int kb = beg[node], ke = endp[node];
    float acc[8];
    #pragma unroll
    for (int i = 0; i < 8; ++i) acc[i] = 0.f;

    for (int k0 = kb; k0 < ke; k0 += 64) {
        int kk = k0 + lane;
        int s = (kk < ke) ? srcList[kk] : 0;
        int cnt = min(64, ke - k0);
        int nf = cnt >> 3;
        #pragma unroll 2
        for (int j = 0; j < nf; ++j) {
            int sj = __shfl(s, (j << 3) + g, 64);
            uint4 hv = Hv[(size_t)sj * 8 + c8];
            addbf8(acc, hv);
        }
        int rem = cnt & 7;
        if (rem) {
            int sj = __shfl(s, min((nf << 3) + g, 63), 64);
            if (g < rem) {
                uint4 hv = Hv[(size_t)sj * 8 + c8];
                addbf8(acc, hv);
            }
        }
    }

    // self-loop term
    {
        uint4 sv = Hv[(size_t)node * 8 + c8];
        addbf8(acc, sv);
    }

    // reduce across the 8 groups (same c8 -> same features)
    #pragma unroll
    for (int off = 8; off < 64; off <<= 1) {
        #pragma unroll
        for (int i = 0; i < 8; ++i) acc[i] += __shfl_xor(acc[i], off, 64);
    }
    // NOTE: self term was added by all 8 groups -> counted 8x. Compensate:
    // subtract 7x self AFTER reduce (each lane still has its sv chunk).
    {
        uint4 sv = Hv[(size_t)node * 8 + c8];
        float s8[8] = {bflo(sv.x), bfhi(sv.x), bflo(sv.y), bfhi(sv.y),
                       bflo(sv.z), bfhi(sv.z), bflo(sv.w), bfhi(sv.w)};
        #pragma unroll
        for (int i = 0; i < 8; ++i) acc[i] -= 7.f * s8[i];
    }

    const float di = dinv[node];
    const float4* bv = reinterpret_cast<const float4*>(bias);
    float4 b0 = bv[c8 * 2], b1 = bv[c8 * 2 + 1];
    float r[8];
    r[0] = fmaf(di, acc[0], b0.x); r[1] = fmaf(di, acc[1], b0.y);
    r[2] = fmaf(di, acc[2], b0.z); r[3] = fmaf(di, acc[3], b0.w);
    r[4] = fmaf(di, acc[4], b1.x); r[5] = fmaf(di, acc[5], b1.y);
    r[6] = fmaf(di, acc[6], b1.z); r[7] = fmaf(di, acc[7], b1.w);
    if (do_relu) {
        #pragma unroll
        for (int i = 0; i < 8; ++i) r[i] = fmaxf(r[i], 0.f);
    }
    if (lane < 8) {
        if (Ob) {
            uint4 o;
            o.x = f2bf(r[0]) | (f2bf(r[1]) << 16);
            o.y = f2bf(r[2]) | (f2bf(r[3]) << 16);
            o.z = f2bf(r[4]) | (f2bf(r[5]) << 16);
            o.w = f2bf(r[6]) | (f2bf(r[7]) << 16);
            reinterpret_cast<uint4*>(Ob)[(size_t)node * 8 + c8] = o;
        } else {
            float4 o0 = make_float4(r[0], r[1], r[2], r[3]);
            float4 o1 = make_float4(r[4], r[5], r[6], r[7]);
            reinterpret_cast<float4*>(Of)[(size_t)node * 16 + c8 * 2]     = o0;
            reinterpret_cast<float4*>(Of)[(size_t)node * 16 + c8 * 2 + 1] = o1;
        }
    }
}

extern "C" void kernel_launch(void* const* d_in, const int* in_sizes, int n_in,
                              void* d_out, int out_size, void* d_ws, size_t ws_size,
                              hipStream_t stream) {
    const float* x  = (const float*)d_in[0];
    const int*   ei = (const int*)  d_in[1];   // [2, E], int32
    const float* W1 = (const float*)d_in[2];
    const float* b1 = (const float*)d_in[3];
    const float* W2 = (const float*)d_in[4];
    const float* b2 = (const float*)d_in[5];
    float* out = (float*)d_out;

    const int N = in_sizes[0] / FDIM;   // 100000
    const int E = in_sizes[1] / 2;      // 1600000
    const int* src = ei;
    const int* dst = ei + E;

    const int nB = (N + BNODES - 1) >> BSHIFT;   // 196

    auto align1k = [](size_t v) { return (v + 1023) & ~(size_t)1023; };
    char* p = (char*)d_ws;
    int*      gCursor = (int*)p;        p += align1k(256 * 4);
    float*    dinv    = (float*)p;      p += align1k((size_t)N * 4);
    int*      beg     = (int*)p;        p += align1k((size_t)N * 4);
    int*      endp    = (int*)p;        p += align1k((size_t)N * 4);
    unsigned* pairs   = (unsigned*)p;   p += align1k((size_t)nB * BCAP * 4);
    bf16_t*   H       = (bf16_t*)p;     p += align1k((size_t)N * FDIM * 2);
    bf16_t*   Y       = (bf16_t*)p;     // N*64 bf16 (layer-1 activations)

    // ---- CSR build via bucket + LDS counting sort ----
    hipMemsetAsync(gCursor, 0, 256 * 4, stream);
    k_bucket<<<(E + EPB - 1) / EPB, 256, 0, stream>>>(src, dst, gCursor, pairs, E, N);
    k_sort<<<nB, 1024, 0, stream>>>(pairs, gCursor, dinv, beg, endp, N);

    const int gemmBlocks = (N + 63) / 64;
    const int aggBlocks  = (N + 3) / 4;
    const int* srcList = (const int*)pairs;

    // ---- layer 1 ----
    k_gemm_f32<<<gemmBlocks, 256, 0, stream>>>(x, W1, dinv, H, N);
    k_agg<<<aggBlocks, 256, 0, stream>>>(H, srcList, beg, endp, dinv, b1,
                                         nullptr, Y, N, 1);

    // ---- layer 2 ----
    k_gemm_bf16<<<gemmBlocks, 256, 0, stream>>>(Y, W2, dinv, H, N);
    k_agg<<<aggBlocks, 256, 0, stream>>>(H, srcList, beg, endp, dinv, b2,
                                         out, nullptr, N, 0);
}

// Round 6
// 177.092 us; speedup vs baseline: 8.6937x; 1.1348x over previous
//
#include <hip/hip_runtime.h>

#define FDIM   64
#define BSHIFT 9            // 512 nodes per bucket
#define BNODES 512
#define BCAP   8960         // slots per bucket (mean 8163, sd ~90 -> +8.8 sigma)
#define EPB    4096         // edges per k_bucket block

typedef unsigned short bf16_t;

__device__ __forceinline__ float bflo(unsigned u) { return __uint_as_float(u << 16); }
__device__ __forceinline__ float bfhi(unsigned u) { return __uint_as_float(u & 0xFFFF0000u); }
__device__ __forceinline__ unsigned f2bf(float f) {   // RNE, returns low 16 bits
    unsigned u = __float_as_uint(f);
    u += 0x7FFFu + ((u >> 16) & 1u);
    return u >> 16;
}
__device__ __forceinline__ void addbf8(float* acc, uint4 v) {
    acc[0] += bflo(v.x); acc[1] += bfhi(v.x);
    acc[2] += bflo(v.y); acc[3] += bfhi(v.y);
    acc[4] += bflo(v.z); acc[5] += bfhi(v.z);
    acc[6] += bflo(v.w); acc[7] += bfhi(v.w);
}

// ---------------- pass A: bucket edges by dst, pack (localDst<<17 | src) ----------------
__global__ __launch_bounds__(256) void k_bucket(const int* __restrict__ src,
                                                const int* __restrict__ dst,
                                                int* __restrict__ gCursor,
                                                unsigned* __restrict__ pairs,
                                                int E, int N) {
    __shared__ int cnt[256];
    __shared__ int base[256];
    __shared__ int cur[256];
    const int t  = threadIdx.x;
    const int e0 = blockIdx.x * EPB;
    cnt[t] = 0; cur[t] = 0;
    __syncthreads();

    #pragma unroll 4
    for (int i = 0; i < EPB / 256; ++i) {
        int e = e0 + i * 256 + t;
        if (e < E) {
            int d = dst[e];
            d = min(max(d, 0), N - 1);
            atomicAdd(&cnt[d >> BSHIFT], 1);
        }
    }
    __syncthreads();
    if (cnt[t] > 0) base[t] = atomicAdd(&gCursor[t], cnt[t]);
    __syncthreads();
    #pragma unroll 4
    for (int i = 0; i < EPB / 256; ++i) {
        int e = e0 + i * 256 + t;
        if (e < E) {
            int d = dst[e], s = src[e];
            d = min(max(d, 0), N - 1);
            s = min(max(s, 0), N - 1);
            int b = d >> BSHIFT;
            int slot = base[b] + atomicAdd(&cur[b], 1);
            if (slot < BCAP)
                pairs[(size_t)b * BCAP + slot] =
                    ((unsigned)(d & (BNODES - 1)) << 17) | (unsigned)s;
        }
    }
}

// ---------------- pass B: per-bucket counting sort (in LDS), in-place scatter ----------------
__global__ __launch_bounds__(1024) void k_sort(unsigned* __restrict__ pairs,
                                               const int* __restrict__ gCursor,
                                               float* __restrict__ dinv,
                                               int* __restrict__ beg,
                                               int* __restrict__ endp,
                                               int N) {
    __shared__ unsigned buf[BCAP];     // 35 KB
    __shared__ int cnt[BNODES];
    __shared__ int scn[BNODES];
    __shared__ int cur[BNODES];
    const int b = blockIdx.x, t = threadIdx.x;
    const int count = min(gCursor[b], BCAP);
    unsigned* p = pairs + (size_t)b * BCAP;

    if (t < BNODES) cnt[t] = 0;
    __syncthreads();
    for (int i = t; i < count; i += 1024) {
        unsigned pk = p[i];
        buf[i] = pk;
        atomicAdd(&cnt[pk >> 17], 1);
    }
    __syncthreads();
    if (t < BNODES) scn[t] = cnt[t];
    __syncthreads();
    for (int off = 1; off < BNODES; off <<= 1) {
        int v = 0;
        if (t < BNODES && t >= off) v = scn[t - off];
        __syncthreads();
        if (t < BNODES) scn[t] += v;
        __syncthreads();
    }
    if (t < BNODES) {
        int c  = cnt[t];
        int st = scn[t] - c;
        cur[t] = st;
        int n = (b << BSHIFT) + t;
        if (n < N) {
            beg[n]  = b * BCAP + st;
            endp[n] = b * BCAP + st + c;
            dinv[n] = rsqrtf((float)(c + 1));
        }
    }
    __syncthreads();
    for (int i = t; i < count; i += 1024) {
        unsigned pk = buf[i];
        int pos = atomicAdd(&cur[pk >> 17], 1);
        p[pos] = pk & 0x1FFFFu;
    }
}

// ---------------- GEMM (fp32 in): Ob[r] = bf16( dinv[r] * (X @ W)[r] ) ----------------
__global__ __launch_bounds__(256) void k_gemm_f32(const float* __restrict__ X,
                                                  const float* __restrict__ W,
                                                  const float* __restrict__ dinv,
                                                  bf16_t* __restrict__ Ob, int N) {
    __shared__ float Xs[64][FDIM];
    __shared__ float Ws[64][FDIM];
    const int tid  = threadIdx.x;
    const int base = blockIdx.x * 64;

    #pragma unroll
    for (int i = 0; i < 4; ++i) {
        int idx = tid + i * 256;
        reinterpret_cast<float4*>(&Ws[0][0])[idx] =
            reinterpret_cast<const float4*>(W)[idx];
    }
    #pragma unroll
    for (int i = 0; i < 4; ++i) {
        int idx = tid + i * 256;
        int r = idx >> 4;
        int gr = base + r;
        float4 v = make_float4(0.f, 0.f, 0.f, 0.f);
        if (gr < N) v = reinterpret_cast<const float4*>(X)[(size_t)gr * 16 + (idx & 15)];
        reinterpret_cast<float4*>(&Xs[0][0])[idx] = v;
    }
    __syncthreads();

    const int c  = tid & 63;
    const int rq = tid >> 6;
    float acc[16];
    #pragma unroll
    for (int j = 0; j < 16; ++j) acc[j] = 0.f;

    #pragma unroll 8
    for (int k = 0; k < 64; ++k) {
        float wv = Ws[k][c];
        #pragma unroll
        for (int j = 0; j < 16; ++j)
            acc[j] = fmaf(Xs[rq * 16 + j][k], wv, acc[j]);
    }

    #pragma unroll
    for (int j = 0; j < 16; ++j) {
        int gr = base + rq * 16 + j;
        if (gr < N) Ob[(size_t)gr * FDIM + c] = (bf16_t)f2bf(acc[j] * dinv[gr]);
    }
}

// ---------------- GEMM (bf16 in): Ob[r] = bf16( dinv[r] * (Y @ W)[r] ) ----------------
__global__ __launch_bounds__(256) void k_gemm_bf16(const bf16_t* __restrict__ Y,
                                                   const float* __restrict__ W,
                                                   const float* __restrict__ dinv,
                                                   bf16_t* __restrict__ Ob, int N) {
    __shared__ float Xs[64][FDIM];
    __shared__ float Ws[64][FDIM];
    const int tid  = threadIdx.x;
    const int base = blockIdx.x * 64;

    #pragma unroll
    for (int i = 0; i < 4; ++i) {
        int idx = tid + i * 256;
        reinterpret_cast<float4*>(&Ws[0][0])[idx] =
            reinterpret_cast<const float4*>(W)[idx];
    }
    #pragma unroll
    for (int i = 0; i < 2; ++i) {
        int idx = tid + i * 256;
        int r = idx >> 3, ci = idx & 7;
        int gr = base + r;
        uint4 v = make_uint4(0u, 0u, 0u, 0u);
        if (gr < N) v = reinterpret_cast<const uint4*>(Y)[(size_t)gr * 8 + ci];
        float* xp = &Xs[r][ci * 8];
        xp[0] = bflo(v.x); xp[1] = bfhi(v.x);
        xp[2] = bflo(v.y); xp[3] = bfhi(v.y);
        xp[4] = bflo(v.z); xp[5] = bfhi(v.z);
        xp[6] = bflo(v.w); xp[7] = bfhi(v.w);
    }
    __syncthreads();

    const int c  = tid & 63;
    const int rq = tid >> 6;
    float acc[16];
    #pragma unroll
    for (int j = 0; j < 16; ++j) acc[j] = 0.f;

    #pragma unroll 8
    for (int k = 0; k < 64; ++k) {
        float wv = Ws[k][c];
        #pragma unroll
        for (int j = 0; j < 16; ++j)
            acc[j] = fmaf(Xs[rq * 16 + j][k], wv, acc[j]);
    }

    #pragma unroll
    for (int j = 0; j < 16; ++j) {
        int gr = base + rq * 16 + j;
        if (gr < N) Ob[(size_t)gr * FDIM + c] = (bf16_t)f2bf(acc[j] * dinv[gr]);
    }
}

// ---------------- CSR gather-aggregate (bf16 rows), 4 nodes per wave ----------------
// 8 groups of 8 lanes = 4 nodes x 2 edge-slots; group loads its edge src directly
// (same-address broadcast, no shfl), gathers a 16B row chunk, accumulates fp32.
// One shfl_xor(8) round merges the two slots. Self-term + bias + relu fused.
__global__ __launch_bounds__(256) void k_agg(const bf16_t* __restrict__ Hs,
                                             const int* __restrict__ srcList,
                                             const int* __restrict__ beg,
                                             const int* __restrict__ endp,
                                             const float* __restrict__ dinv,
                                             const float* __restrict__ bias,
                                             float* __restrict__ Of,
                                             bf16_t* __restrict__ Ob,
                                             int N, int do_relu) {
    const int lane = threadIdx.x & 63;
    const int w    = threadIdx.x >> 6;        // wave 0..3
    const int g    = lane >> 3;               // group 0..7
    const int c8   = lane & 7;                // uint4 chunk of row
    const int nl   = g >> 1;                  // node-in-wave 0..3
    const int par  = g & 1;                   // edge-slot parity
    const int node = (blockIdx.x * 4 + w) * 4 + nl;

    const uint4* Hv = reinterpret_cast<const uint4*>(Hs) + c8;

    int kb = 0, ke = 0;
    if (node < N) { kb = beg[node]; ke = endp[node]; }

    float acc[8];
    #pragma unroll
    for (int i = 0; i < 8; ++i) acc[i] = 0.f;

    int k = kb + par;
    for (; k + 2 < ke; k += 4) {          // two independent gather chains
        int s0 = srcList[k];
        int s1 = srcList[k + 2];
        uint4 h0 = Hv[(size_t)s0 * 8];
        uint4 h1 = Hv[(size_t)s1 * 8];
        addbf8(acc, h0);
        addbf8(acc, h1);
    }
    if (k < ke) {
        uint4 h0 = Hv[(size_t)srcList[k] * 8];
        addbf8(acc, h0);
    }

    // merge the two edge-slots of this node
    #pragma unroll
    for (int i = 0; i < 8; ++i) acc[i] += __shfl_xor(acc[i], 8, 64);

    if (node >= N) return;

    // self-loop term (both parities compute identical values)
    uint4 sv = Hv[(size_t)node * 8];
    addbf8(acc, sv);

    const float di = dinv[node];
    const float4* bv = reinterpret_cast<const float4*>(bias);
    float4 b0 = bv[c8 * 2], b1 = bv[c8 * 2 + 1];
    float r[8];
    r[0] = fmaf(di, acc[0], b0.x); r[1] = fmaf(di, acc[1], b0.y);
    r[2] = fmaf(di, acc[2], b0.z); r[3] = fmaf(di, acc[3], b0.w);
    r[4] = fmaf(di, acc[4], b1.x); r[5] = fmaf(di, acc[5], b1.y);
    r[6] = fmaf(di, acc[6], b1.z); r[7] = fmaf(di, acc[7], b1.w);
    if (do_relu) {
        #pragma unroll
        for (int i = 0; i < 8; ++i) r[i] = fmaxf(r[i], 0.f);
    }
    if (par == 0) {
        if (Ob) {
            uint4 o;
            o.x = f2bf(r[0]) | (f2bf(r[1]) << 16);
            o.y = f2bf(r[2]) | (f2bf(r[3]) << 16);
            o.z = f2bf(r[4]) | (f2bf(r[5]) << 16);
            o.w = f2bf(r[6]) | (f2bf(r[7]) << 16);
            reinterpret_cast<uint4*>(Ob)[(size_t)node * 8 + c8] = o;
        } else {
            float4 o0 = make_float4(r[0], r[1], r[2], r[3]);
            float4 o1 = make_float4(r[4], r[5], r[6], r[7]);
            reinterpret_cast<float4*>(Of)[(size_t)node * 16 + c8 * 2]     = o0;
            reinterpret_cast<float4*>(Of)[(size_t)node * 16 + c8 * 2 + 1] = o1;
        }
    }
}

extern "C" void kernel_launch(void* const* d_in, const int* in_sizes, int n_in,
                              void* d_out, int out_size, void* d_ws, size_t ws_size,
                              hipStream_t stream) {
    const float* x  = (const float*)d_in[0];
    const int*   ei = (const int*)  d_in[1];   // [2, E], int32
    const float* W1 = (const float*)d_in[2];
    const float* b1 = (const float*)d_in[3];
    const float* W2 = (const float*)d_in[4];
    const float* b2 = (const float*)d_in[5];
    float* out = (float*)d_out;

    const int N = in_sizes[0] / FDIM;   // 100000
    const int E = in_sizes[1] / 2;      // 1600000
    const int* src = ei;
    const int* dst = ei + E;

    const int nB = (N + BNODES - 1) >> BSHIFT;   // 196

    auto align1k = [](size_t v) { return (v + 1023) & ~(size_t)1023; };
    char* p = (char*)d_ws;
    int*      gCursor = (int*)p;        p += align1k(256 * 4);
    float*    dinv    = (float*)p;      p += align1k((size_t)N * 4);
    int*      beg     = (int*)p;        p += align1k((size_t)N * 4);
    int*      endp    = (int*)p;        p += align1k((size_t)N * 4);
    unsigned* pairs   = (unsigned*)p;   p += align1k((size_t)nB * BCAP * 4);
    bf16_t*   H       = (bf16_t*)p;     p += align1k((size_t)N * FDIM * 2);
    bf16_t*   Y       = (bf16_t*)p;     // N*64 bf16 (layer-1 activations)

    // ---- CSR build via bucket + LDS counting sort ----
    hipMemsetAsync(gCursor, 0, 256 * 4, stream);
    k_bucket<<<(E + EPB - 1) / EPB, 256, 0, stream>>>(src, dst, gCursor, pairs, E, N);
    k_sort<<<nB, 1024, 0, stream>>>(pairs, gCursor, dinv, beg, endp, N);

    const int gemmBlocks = (N + 63) / 64;
    const int aggBlocks  = (N + 15) / 16;      // 16 nodes per block (4 per wave)
    const int* srcList = (const int*)pairs;

    // ---- layer 1 ----
    k_gemm_f32<<<gemmBlocks, 256, 0, stream>>>(x, W1, dinv, H, N);
    k_agg<<<aggBlocks, 256, 0, stream>>>(H, srcList, beg, endp, dinv, b1,
                                         nullptr, Y, N, 1);

    // ---- layer 2 ----
    k_gemm_bf16<<<gemmBlocks, 256, 0, stream>>>(Y, W2, dinv, H, N);
    k_agg<<<aggBlocks, 256, 0, stream>>>(H, srcList, beg, endp, dinv, b2,
                                         out, nullptr, N, 0);
}

// Round 7
// 176.155 us; speedup vs baseline: 8.7399x; 1.0053x over previous
//
#include <hip/hip_runtime.h>

#define FDIM   64
#define BSHIFT 9            // 512 nodes per bucket
#define BNODES 512
#define BCAP   8960         // slots per bucket (mean 8163, sd ~90 -> +8.8 sigma)
#define EPB    4096         // edges per k_bucket block

typedef unsigned short bf16_t;

__device__ __forceinline__ float bflo(unsigned u) { return __uint_as_float(u << 16); }
__device__ __forceinline__ float bfhi(unsigned u) { return __uint_as_float(u & 0xFFFF0000u); }
__device__ __forceinline__ unsigned f2bf(float f) {   // RNE, returns low 16 bits
    unsigned u = __float_as_uint(f);
    u += 0x7FFFu + ((u >> 16) & 1u);
    return u >> 16;
}
__device__ __forceinline__ void addbf8(float* acc, uint4 v) {
    acc[0] += bflo(v.x); acc[1] += bfhi(v.x);
    acc[2] += bflo(v.y); acc[3] += bfhi(v.y);
    acc[4] += bflo(v.z); acc[5] += bfhi(v.z);
    acc[6] += bflo(v.w); acc[7] += bfhi(v.w);
}

// ---------------- zero the 256-int global cursor (hipMemsetAsync blit costs ~40us) ----
__global__ void k_zero(int* __restrict__ g) { g[threadIdx.x] = 0; }

// ---------------- pass A: bucket edges by dst, pack (localDst<<17 | src) ----------------
__global__ __launch_bounds__(256) void k_bucket(const int* __restrict__ src,
                                                const int* __restrict__ dst,
                                                int* __restrict__ gCursor,
                                                unsigned* __restrict__ pairs,
                                                int E, int N) {
    __shared__ int cnt[256];
    __shared__ int base[256];
    __shared__ int cur[256];
    const int t  = threadIdx.x;
    const int e0 = blockIdx.x * EPB;
    int dcache[EPB / 256];
    cnt[t] = 0; cur[t] = 0;
    __syncthreads();

    // phase 1: count buckets, cache clamped dst in registers
    #pragma unroll 4
    for (int i = 0; i < EPB / 256; ++i) {
        int e = e0 + i * 256 + t;
        int d = -1;
        if (e < E) {
            d = dst[e];
            d = min(max(d, 0), N - 1);
            atomicAdd(&cnt[d >> BSHIFT], 1);
        }
        dcache[i] = d;
    }
    __syncthreads();
    // phase 2: reserve global ranges
    if (cnt[t] > 0) base[t] = atomicAdd(&gCursor[t], cnt[t]);
    __syncthreads();
    // phase 3: write packed pairs (dst from registers)
    #pragma unroll 4
    for (int i = 0; i < EPB / 256; ++i) {
        int d = dcache[i];
        if (d >= 0) {
            int e = e0 + i * 256 + t;
            int s = src[e];
            s = min(max(s, 0), N - 1);
            int b = d >> BSHIFT;
            int slot = base[b] + atomicAdd(&cur[b], 1);
            if (slot < BCAP)
                pairs[(size_t)b * BCAP + slot] =
                    ((unsigned)(d & (BNODES - 1)) << 17) | (unsigned)s;
        }
    }
}

// ---------------- pass B: per-bucket counting sort (in LDS), in-place scatter ----------------
__global__ __launch_bounds__(1024) void k_sort(unsigned* __restrict__ pairs,
                                               const int* __restrict__ gCursor,
                                               float* __restrict__ dinv,
                                               int* __restrict__ beg,
                                               int* __restrict__ endp,
                                               int N) {
    __shared__ unsigned buf[BCAP];     // 35 KB
    __shared__ int cnt[BNODES];
    __shared__ int scn[BNODES];
    __shared__ int cur[BNODES];
    const int b = blockIdx.x, t = threadIdx.x;
    const int count = min(gCursor[b], BCAP);
    unsigned* p = pairs + (size_t)b * BCAP;

    if (t < BNODES) cnt[t] = 0;
    __syncthreads();
    for (int i = t; i < count; i += 1024) {
        unsigned pk = p[i];
        buf[i] = pk;
        atomicAdd(&cnt[pk >> 17], 1);
    }
    __syncthreads();
    if (t < BNODES) scn[t] = cnt[t];
    __syncthreads();
    for (int off = 1; off < BNODES; off <<= 1) {
        int v = 0;
        if (t < BNODES && t >= off) v = scn[t - off];
        __syncthreads();
        if (t < BNODES) scn[t] += v;
        __syncthreads();
    }
    if (t < BNODES) {
        int c  = cnt[t];
        int st = scn[t] - c;
        cur[t] = st;
        int n = (b << BSHIFT) + t;
        if (n < N) {
            beg[n]  = b * BCAP + st;
            endp[n] = b * BCAP + st + c;
            dinv[n] = rsqrtf((float)(c + 1));
        }
    }
    __syncthreads();
    for (int i = t; i < count; i += 1024) {
        unsigned pk = buf[i];
        int pos = atomicAdd(&cur[pk >> 17], 1);
        p[pos] = pk & 0x1FFFFu;
    }
}

// ---------------- GEMM (fp32 in): Ob[r] = bf16( dinv[r] * (X @ W)[r] ) ----------------
__global__ __launch_bounds__(256) void k_gemm_f32(const float* __restrict__ X,
                                                  const float* __restrict__ W,
                                                  const float* __restrict__ dinv,
                                                  bf16_t* __restrict__ Ob, int N) {
    __shared__ float Xs[64][FDIM];
    __shared__ float Ws[64][FDIM];
    const int tid  = threadIdx.x;
    const int base = blockIdx.x * 64;

    #pragma unroll
    for (int i = 0; i < 4; ++i) {
        int idx = tid + i * 256;
        reinterpret_cast<float4*>(&Ws[0][0])[idx] =
            reinterpret_cast<const float4*>(W)[idx];
    }
    #pragma unroll
    for (int i = 0; i < 4; ++i) {
        int idx = tid + i * 256;
        int r = idx >> 4;
        int gr = base + r;
        float4 v = make_float4(0.f, 0.f, 0.f, 0.f);
        if (gr < N) v = reinterpret_cast<const float4*>(X)[(size_t)gr * 16 + (idx & 15)];
        reinterpret_cast<float4*>(&Xs[0][0])[idx] = v;
    }
    __syncthreads();

    const int c  = tid & 63;
    const int rq = tid >> 6;
    float acc[16];
    #pragma unroll
    for (int j = 0; j < 16; ++j) acc[j] = 0.f;

    #pragma unroll 8
    for (int k = 0; k < 64; ++k) {
        float wv = Ws[k][c];
        #pragma unroll
        for (int j = 0; j < 16; ++j)
            acc[j] = fmaf(Xs[rq * 16 + j][k], wv, acc[j]);
    }

    #pragma unroll
    for (int j = 0; j < 16; ++j) {
        int gr = base + rq * 16 + j;
        if (gr < N) Ob[(size_t)gr * FDIM + c] = (bf16_t)f2bf(acc[j] * dinv[gr]);
    }
}

// ---------------- GEMM (bf16 in): Ob[r] = bf16( dinv[r] * (Y @ W)[r] ) ----------------
__global__ __launch_bounds__(256) void k_gemm_bf16(const bf16_t* __restrict__ Y,
                                                   const float* __restrict__ W,
                                                   const float* __restrict__ dinv,
                                                   bf16_t* __restrict__ Ob, int N) {
    __shared__ float Xs[64][FDIM];
    __shared__ float Ws[64][FDIM];
    const int tid  = threadIdx.x;
    const int base = blockIdx.x * 64;

    #pragma unroll
    for (int i = 0; i < 4; ++i) {
        int idx = tid + i * 256;
        reinterpret_cast<float4*>(&Ws[0][0])[idx] =
            reinterpret_cast<const float4*>(W)[idx];
    }
    #pragma unroll
    for (int i = 0; i < 2; ++i) {
        int idx = tid + i * 256;
        int r = idx >> 3, ci = idx & 7;
        int gr = base + r;
        uint4 v = make_uint4(0u, 0u, 0u, 0u);
        if (gr < N) v = reinterpret_cast<const uint4*>(Y)[(size_t)gr * 8 + ci];
        float* xp = &Xs[r][ci * 8];
        xp[0] = bflo(v.x); xp[1] = bfhi(v.x);
        xp[2] = bflo(v.y); xp[3] = bfhi(v.y);
        xp[4] = bflo(v.z); xp[5] = bfhi(v.z);
        xp[6] = bflo(v.w); xp[7] = bfhi(v.w);
    }
    __syncthreads();

    const int c  = tid & 63;
    const int rq = tid >> 6;
    float acc[16];
    #pragma unroll
    for (int j = 0; j < 16; ++j) acc[j] = 0.f;

    #pragma unroll 8
    for (int k = 0; k < 64; ++k) {
        float wv = Ws[k][c];
        #pragma unroll
        for (int j = 0; j < 16; ++j)
            acc[j] = fmaf(Xs[rq * 16 + j][k], wv, acc[j]);
    }

    #pragma unroll
    for (int j = 0; j < 16; ++j) {
        int gr = base + rq * 16 + j;
        if (gr < N) Ob[(size_t)gr * FDIM + c] = (bf16_t)f2bf(acc[j] * dinv[gr]);
    }
}

// ---------------- CSR gather-aggregate (bf16 rows), 4 nodes per wave ----------------
__global__ __launch_bounds__(256) void k_agg(const bf16_t* __restrict__ Hs,
                                             const int* __restrict__ srcList,
                                             const int* __restrict__ beg,
                                             const int* __restrict__ endp,
                                             const float* __restrict__ dinv,
                                             const float* __restrict__ bias,
                                             float* __restrict__ Of,
                                             bf16_t* __restrict__ Ob,
                                             int N, int do_relu) {
    const int lane = threadIdx.x & 63;
    const int w    = threadIdx.x >> 6;        // wave 0..3
    const int g    = lane >> 3;               // group 0..7
    const int c8   = lane & 7;                // uint4 chunk of row
    const int nl   = g >> 1;                  // node-in-wave 0..3
    const int par  = g & 1;                   // edge-slot parity
    const int node = (blockIdx.x * 4 + w) * 4 + nl;

    const uint4* Hv = reinterpret_cast<const uint4*>(Hs) + c8;

    int kb = 0, ke = 0;
    if (node < N) { kb = beg[node]; ke = endp[node]; }

    float acc[8];
    #pragma unroll
    for (int i = 0; i < 8; ++i) acc[i] = 0.f;

    int k = kb + par;
    for (; k + 2 < ke; k += 4) {          // two independent gather chains
        int s0 = srcList[k];
        int s1 = srcList[k + 2];
        uint4 h0 = Hv[(size_t)s0 * 8];
        uint4 h1 = Hv[(size_t)s1 * 8];
        addbf8(acc, h0);
        addbf8(acc, h1);
    }
    if (k < ke) {
        uint4 h0 = Hv[(size_t)srcList[k] * 8];
        addbf8(acc, h0);
    }

    // merge the two edge-slots of this node
    #pragma unroll
    for (int i = 0; i < 8; ++i) acc[i] += __shfl_xor(acc[i], 8, 64);

    if (node >= N) return;

    // self-loop term (both parities compute identical values)
    uint4 sv = Hv[(size_t)node * 8];
    addbf8(acc, sv);

    const float di = dinv[node];
    const float4* bv = reinterpret_cast<const float4*>(bias);
    float4 b0 = bv[c8 * 2], b1 = bv[c8 * 2 + 1];
    float r[8];
    r[0] = fmaf(di, acc[0], b0.x); r[1] = fmaf(di, acc[1], b0.y);
    r[2] = fmaf(di, acc[2], b0.z); r[3] = fmaf(di, acc[3], b0.w);
    r[4] = fmaf(di, acc[4], b1.x); r[5] = fmaf(di, acc[5], b1.y);
    r[6] = fmaf(di, acc[6], b1.z); r[7] = fmaf(di, acc[7], b1.w);
    if (do_relu) {
        #pragma unroll
        for (int i = 0; i < 8; ++i) r[i] = fmaxf(r[i], 0.f);
    }
    if (par == 0) {
        if (Ob) {
            uint4 o;
            o.x = f2bf(r[0]) | (f2bf(r[1]) << 16);
            o.y = f2bf(r[2]) | (f2bf(r[3]) << 16);
            o.z = f2bf(r[4]) | (f2bf(r[5]) << 16);
            o.w = f2bf(r[6]) | (f2bf(r[7]) << 16);
            reinterpret_cast<uint4*>(Ob)[(size_t)node * 8 + c8] = o;
        } else {
            float4 o0 = make_float4(r[0], r[1], r[2], r[3]);
            float4 o1 = make_float4(r[4], r[5], r[6], r[7]);
            reinterpret_cast<float4*>(Of)[(size_t)node * 16 + c8 * 2]     = o0;
            reinterpret_cast<float4*>(Of)[(size_t)node * 16 + c8 * 2 + 1] = o1;
        }
    }
}

extern "C" void kernel_launch(void* const* d_in, const int* in_sizes, int n_in,
                              void* d_out, int out_size, void* d_ws, size_t ws_size,
                              hipStream_t stream) {
    const float* x  = (const float*)d_in[0];
    const int*   ei = (const int*)  d_in[1];   // [2, E], int32
    const float* W1 = (const float*)d_in[2];
    const float* b1 = (const float*)d_in[3];
    const float* W2 = (const float*)d_in[4];
    const float* b2 = (const float*)d_in[5];
    float* out = (float*)d_out;

    const int N = in_sizes[0] / FDIM;   // 100000
    const int E = in_sizes[1] / 2;      // 1600000
    const int* src = ei;
    const int* dst = ei + E;

    const int nB = (N + BNODES - 1) >> BSHIFT;   // 196

    auto align1k = [](size_t v) { return (v + 1023) & ~(size_t)1023; };
    char* p = (char*)d_ws;
    int*      gCursor = (int*)p;        p += align1k(256 * 4);
    float*    dinv    = (float*)p;      p += align1k((size_t)N * 4);
    int*      beg     = (int*)p;        p += align1k((size_t)N * 4);
    int*      endp    = (int*)p;        p += align1k((size_t)N * 4);
    unsigned* pairs   = (unsigned*)p;   p += align1k((size_t)nB * BCAP * 4);
    bf16_t*   H       = (bf16_t*)p;     p += align1k((size_t)N * FDIM * 2);
    bf16_t*   Y       = (bf16_t*)p;     // N*64 bf16 (layer-1 activations)

    // ---- CSR build via bucket + LDS counting sort ----
    k_zero<<<1, 256, 0, stream>>>(gCursor);
    k_bucket<<<(E + EPB - 1) / EPB, 256, 0, stream>>>(src, dst, gCursor, pairs, E, N);
    k_sort<<<nB, 1024, 0, stream>>>(pairs, gCursor, dinv, beg, endp, N);

    const int gemmBlocks = (N + 63) / 64;
    const int aggBlocks  = (N + 15) / 16;      // 16 nodes per block (4 per wave)
    const int* srcList = (const int*)pairs;

    // ---- layer 1 ----
    k_gemm_f32<<<gemmBlocks, 256, 0, stream>>>(x, W1, dinv, H, N);
    k_agg<<<aggBlocks, 256, 0, stream>>>(H, srcList, beg, endp, dinv, b1,
                                         nullptr, Y, N, 1);

    // ---- layer 2 ----
    k_gemm_bf16<<<gemmBlocks, 256, 0, stream>>>(Y, W2, dinv, H, N);
    k_agg<<<aggBlocks, 256, 0, stream>>>(H, srcList, beg, endp, dinv, b2,
                                         out, nullptr, N, 0);
}

// Round 8
// 175.419 us; speedup vs baseline: 8.7766x; 1.0042x over previous
//
#include <hip/hip_runtime.h>

#define FDIM   64
#define BSHIFT 9            // 512 nodes per bucket
#define BNODES 512
#define BCAP   8960         // slots per bucket (mean 8163, sd ~90 -> +8.8 sigma)
#define EPB    4096         // edges per k_bucket block

typedef unsigned short bf16_t;

__device__ __forceinline__ float bflo(unsigned u) { return __uint_as_float(u << 16); }
__device__ __forceinline__ float bfhi(unsigned u) { return __uint_as_float(u & 0xFFFF0000u); }
__device__ __forceinline__ unsigned f2bf(float f) {   // RNE, returns low 16 bits
    unsigned u = __float_as_uint(f);
    u += 0x7FFFu + ((u >> 16) & 1u);
    return u >> 16;
}
__device__ __forceinline__ void addbf8(float* acc, uint4 v) {
    acc[0] += bflo(v.x); acc[1] += bfhi(v.x);
    acc[2] += bflo(v.y); acc[3] += bfhi(v.y);
    acc[4] += bflo(v.z); acc[5] += bfhi(v.z);
    acc[6] += bflo(v.w); acc[7] += bfhi(v.w);
}

// ---------------- zero the 256-int global cursor ----------------
__global__ void k_zero(int* __restrict__ g) { g[threadIdx.x] = 0; }

// ---------------- pass A: bucket edges by dst, pack (localDst<<17 | src) ----------------
__global__ __launch_bounds__(256) void k_bucket(const int* __restrict__ src,
                                                const int* __restrict__ dst,
                                                int* __restrict__ gCursor,
                                                unsigned* __restrict__ pairs,
                                                int E, int N) {
    __shared__ int cnt[256];
    __shared__ int base[256];
    __shared__ int cur[256];
    const int t  = threadIdx.x;
    const int e0 = blockIdx.x * EPB;
    int dcache[EPB / 256];
    cnt[t] = 0; cur[t] = 0;
    __syncthreads();

    #pragma unroll 4
    for (int i = 0; i < EPB / 256; ++i) {
        int e = e0 + i * 256 + t;
        int d = -1;
        if (e < E) {
            d = dst[e];
            d = min(max(d, 0), N - 1);
            atomicAdd(&cnt[d >> BSHIFT], 1);
        }
        dcache[i] = d;
    }
    __syncthreads();
    if (cnt[t] > 0) base[t] = atomicAdd(&gCursor[t], cnt[t]);
    __syncthreads();
    #pragma unroll 4
    for (int i = 0; i < EPB / 256; ++i) {
        int d = dcache[i];
        if (d >= 0) {
            int e = e0 + i * 256 + t;
            int s = src[e];
            s = min(max(s, 0), N - 1);
            int b = d >> BSHIFT;
            int slot = base[b] + atomicAdd(&cur[b], 1);
            if (slot < BCAP)
                pairs[(size_t)b * BCAP + slot] =
                    ((unsigned)(d & (BNODES - 1)) << 17) | (unsigned)s;
        }
    }
}

// ---------------- pass B: per-bucket counting sort (in LDS), in-place scatter ----------------
__global__ __launch_bounds__(1024) void k_sort(unsigned* __restrict__ pairs,
                                               const int* __restrict__ gCursor,
                                               float* __restrict__ dinv,
                                               int* __restrict__ beg,
                                               int* __restrict__ endp,
                                               int N) {
    __shared__ unsigned buf[BCAP];     // 35 KB
    __shared__ int cnt[BNODES];
    __shared__ int scn[BNODES];
    __shared__ int cur[BNODES];
    const int b = blockIdx.x, t = threadIdx.x;
    const int count = min(gCursor[b], BCAP);
    unsigned* p = pairs + (size_t)b * BCAP;

    if (t < BNODES) cnt[t] = 0;
    __syncthreads();
    for (int i = t; i < count; i += 1024) {
        unsigned pk = p[i];
        buf[i] = pk;
        atomicAdd(&cnt[pk >> 17], 1);
    }
    __syncthreads();
    if (t < BNODES) scn[t] = cnt[t];
    __syncthreads();
    for (int off = 1; off < BNODES; off <<= 1) {
        int v = 0;
        if (t < BNODES && t >= off) v = scn[t - off];
        __syncthreads();
        if (t < BNODES) scn[t] += v;
        __syncthreads();
    }
    if (t < BNODES) {
        int c  = cnt[t];
        int st = scn[t] - c;
        cur[t] = st;
        int n = (b << BSHIFT) + t;
        if (n < N) {
            beg[n]  = b * BCAP + st;
            endp[n] = b * BCAP + st + c;
            dinv[n] = rsqrtf((float)(c + 1));
        }
    }
    __syncthreads();
    for (int i = t; i < count; i += 1024) {
        unsigned pk = buf[i];
        int pos = atomicAdd(&cur[pk >> 17], 1);
        p[pos] = pk & 0x1FFFFu;
    }
}

// ---------------- GEMM (fp32 in): Ob[r] = bf16( dinv[r] * (X @ W)[r] ) ----------------
__global__ __launch_bounds__(256) void k_gemm_f32(const float* __restrict__ X,
                                                  const float* __restrict__ W,
                                                  const float* __restrict__ dinv,
                                                  bf16_t* __restrict__ Ob, int N) {
    __shared__ float Xs[64][FDIM];
    __shared__ float Ws[64][FDIM];
    const int tid  = threadIdx.x;
    const int base = blockIdx.x * 64;

    #pragma unroll
    for (int i = 0; i < 4; ++i) {
        int idx = tid + i * 256;
        reinterpret_cast<float4*>(&Ws[0][0])[idx] =
            reinterpret_cast<const float4*>(W)[idx];
    }
    #pragma unroll
    for (int i = 0; i < 4; ++i) {
        int idx = tid + i * 256;
        int r = idx >> 4;
        int gr = base + r;
        float4 v = make_float4(0.f, 0.f, 0.f, 0.f);
        if (gr < N) v = reinterpret_cast<const float4*>(X)[(size_t)gr * 16 + (idx & 15)];
        reinterpret_cast<float4*>(&Xs[0][0])[idx] = v;
    }
    __syncthreads();

    const int c  = tid & 63;
    const int rq = tid >> 6;
    float acc[16];
    #pragma unroll
    for (int j = 0; j < 16; ++j) acc[j] = 0.f;

    #pragma unroll 8
    for (int k = 0; k < 64; ++k) {
        float wv = Ws[k][c];
        #pragma unroll
        for (int j = 0; j < 16; ++j)
            acc[j] = fmaf(Xs[rq * 16 + j][k], wv, acc[j]);
    }

    #pragma unroll
    for (int j = 0; j < 16; ++j) {
        int gr = base + rq * 16 + j;
        if (gr < N) Ob[(size_t)gr * FDIM + c] = (bf16_t)f2bf(acc[j] * dinv[gr]);
    }
}

// ---------------- FUSED: layer-1 aggregate (64 nodes) -> LDS -> layer-2 GEMM ----------------
// Phase 1: per node, acc = sum_s H1[s] (+H1[node]); r = relu(dinv*acc + b1) -> Xs (fp32).
// Phase 2: H2[r] = bf16( dinv[r] * (Xs @ W2)[r] ).
__global__ __launch_bounds__(256) void k_aggemm(const bf16_t* __restrict__ Hs,
                                                const int* __restrict__ srcList,
                                                const int* __restrict__ beg,
                                                const int* __restrict__ endp,
                                                const float* __restrict__ dinv,
                                                const float* __restrict__ bias,
                                                const float* __restrict__ W2,
                                                bf16_t* __restrict__ Ob, int N) {
    __shared__ float Xs[64][FDIM];
    __shared__ float Ws[64][FDIM];
    const int tid  = threadIdx.x;
    const int base = blockIdx.x * 64;

    #pragma unroll
    for (int i = 0; i < 4; ++i) {
        int idx = tid + i * 256;
        reinterpret_cast<float4*>(&Ws[0][0])[idx] =
            reinterpret_cast<const float4*>(W2)[idx];
    }

    const int lane = tid & 63;
    const int w    = tid >> 6;        // wave 0..3
    const int g    = lane >> 3;       // group 0..7
    const int c8   = lane & 7;        // uint4 chunk of row
    const int nl4  = g >> 1;          // node-in-chunk 0..3
    const int par  = g & 1;           // edge-slot parity
    const uint4* Hv = reinterpret_cast<const uint4*>(Hs) + c8;
    const float4* bv = reinterpret_cast<const float4*>(bias);
    const float4 b0 = bv[c8 * 2], b1v = bv[c8 * 2 + 1];

    // phase 1: aggregate 16 nodes per wave (4 chunks of 4)
    for (int chunk = 0; chunk < 4; ++chunk) {
        const int rowL = w * 16 + chunk * 4 + nl4;
        const int node = base + rowL;
        int kb = 0, ke = 0;
        if (node < N) { kb = beg[node]; ke = endp[node]; }

        float acc[8];
        #pragma unroll
        for (int i = 0; i < 8; ++i) acc[i] = 0.f;

        int k = kb + par;
        for (; k + 6 < ke; k += 8) {      // 4 outstanding gathers
            int s0 = srcList[k],     s1 = srcList[k + 2];
            int s2 = srcList[k + 4], s3 = srcList[k + 6];
            uint4 h0 = Hv[(size_t)s0 * 8];
            uint4 h1 = Hv[(size_t)s1 * 8];
            uint4 h2 = Hv[(size_t)s2 * 8];
            uint4 h3 = Hv[(size_t)s3 * 8];
            addbf8(acc, h0); addbf8(acc, h1); addbf8(acc, h2); addbf8(acc, h3);
        }
        for (; k < ke; k += 2) {
            uint4 h0 = Hv[(size_t)srcList[k] * 8];
            addbf8(acc, h0);
        }

        #pragma unroll
        for (int i = 0; i < 8; ++i) acc[i] += __shfl_xor(acc[i], 8, 64);

        if (node < N && par == 0) {
            uint4 sv = Hv[(size_t)node * 8];
            addbf8(acc, sv);
            const float di = dinv[node];
            float4 o0, o1;
            o0.x = fmaxf(fmaf(di, acc[0], b0.x), 0.f);
            o0.y = fmaxf(fmaf(di, acc[1], b0.y), 0.f);
            o0.z = fmaxf(fmaf(di, acc[2], b0.z), 0.f);
            o0.w = fmaxf(fmaf(di, acc[3], b0.w), 0.f);
            o1.x = fmaxf(fmaf(di, acc[4], b1v.x), 0.f);
            o1.y = fmaxf(fmaf(di, acc[5], b1v.y), 0.f);
            o1.z = fmaxf(fmaf(di, acc[6], b1v.z), 0.f);
            o1.w = fmaxf(fmaf(di, acc[7], b1v.w), 0.f);
            *reinterpret_cast<float4*>(&Xs[rowL][c8 * 8])     = o0;
            *reinterpret_cast<float4*>(&Xs[rowL][c8 * 8 + 4]) = o1;
        }
    }
    __syncthreads();

    // phase 2: 64x64 GEMM on the fp32 LDS tile
    const int c  = lane;
    const int rq = w;
    float acc[16];
    #pragma unroll
    for (int j = 0; j < 16; ++j) acc[j] = 0.f;

    #pragma unroll 8
    for (int k = 0; k < 64; ++k) {
        float wv = Ws[k][c];
        #pragma unroll
        for (int j = 0; j < 16; ++j)
            acc[j] = fmaf(Xs[rq * 16 + j][k], wv, acc[j]);
    }

    #pragma unroll
    for (int j = 0; j < 16; ++j) {
        int gr = base + rq * 16 + j;
        if (gr < N) Ob[(size_t)gr * FDIM + c] = (bf16_t)f2bf(acc[j] * dinv[gr]);
    }
}

// ---------------- CSR gather-aggregate (bf16 rows), 4 nodes per wave, fp32 out ----------------
__global__ __launch_bounds__(256) void k_agg(const bf16_t* __restrict__ Hs,
                                             const int* __restrict__ srcList,
                                             const int* __restrict__ beg,
                                             const int* __restrict__ endp,
                                             const float* __restrict__ dinv,
                                             const float* __restrict__ bias,
                                             float* __restrict__ Of,
                                             int N) {
    const int lane = threadIdx.x & 63;
    const int w    = threadIdx.x >> 6;        // wave 0..3
    const int g    = lane >> 3;               // group 0..7
    const int c8   = lane & 7;                // uint4 chunk of row
    const int nl   = g >> 1;                  // node-in-wave 0..3
    const int par  = g & 1;                   // edge-slot parity
    const int node = (blockIdx.x * 4 + w) * 4 + nl;

    const uint4* Hv = reinterpret_cast<const uint4*>(Hs) + c8;

    int kb = 0, ke = 0;
    if (node < N) { kb = beg[node]; ke = endp[node]; }

    float acc[8];
    #pragma unroll
    for (int i = 0; i < 8; ++i) acc[i] = 0.f;

    int k = kb + par;
    for (; k + 6 < ke; k += 8) {          // 4 outstanding gathers
        int s0 = srcList[k],     s1 = srcList[k + 2];
        int s2 = srcList[k + 4], s3 = srcList[k + 6];
        uint4 h0 = Hv[(size_t)s0 * 8];
        uint4 h1 = Hv[(size_t)s1 * 8];
        uint4 h2 = Hv[(size_t)s2 * 8];
        uint4 h3 = Hv[(size_t)s3 * 8];
        addbf8(acc, h0); addbf8(acc, h1); addbf8(acc, h2); addbf8(acc, h3);
    }
    for (; k < ke; k += 2) {
        uint4 h0 = Hv[(size_t)srcList[k] * 8];
        addbf8(acc, h0);
    }

    #pragma unroll
    for (int i = 0; i < 8; ++i) acc[i] += __shfl_xor(acc[i], 8, 64);

    if (node >= N || par != 0) return;

    uint4 sv = Hv[(size_t)node * 8];
    addbf8(acc, sv);

    const float di = dinv[node];
    const float4* bv = reinterpret_cast<const float4*>(bias);
    float4 b0 = bv[c8 * 2], b1 = bv[c8 * 2 + 1];
    float4 o0, o1;
    o0.x = fmaf(di, acc[0], b0.x); o0.y = fmaf(di, acc[1], b0.y);
    o0.z = fmaf(di, acc[2], b0.z); o0.w = fmaf(di, acc[3], b0.w);
    o1.x = fmaf(di, acc[4], b1.x); o1.y = fmaf(di, acc[5], b1.y);
    o1.z = fmaf(di, acc[6], b1.z); o1.w = fmaf(di, acc[7], b1.w);
    reinterpret_cast<float4*>(Of)[(size_t)node * 16 + c8 * 2]     = o0;
    reinterpret_cast<float4*>(Of)[(size_t)node * 16 + c8 * 2 + 1] = o1;
}

extern "C" void kernel_launch(void* const* d_in, const int* in_sizes, int n_in,
                              void* d_out, int out_size, void* d_ws, size_t ws_size,
                              hipStream_t stream) {
    const float* x  = (const float*)d_in[0];
    const int*   ei = (const int*)  d_in[1];   // [2, E], int32
    const float* W1 = (const float*)d_in[2];
    const float* b1 = (const float*)d_in[3];
    const float* W2 = (const float*)d_in[4];
    const float* b2 = (const float*)d_in[5];
    float* out = (float*)d_out;

    const int N = in_sizes[0] / FDIM;   // 100000
    const int E = in_sizes[1] / 2;      // 1600000
    const int* src = ei;
    const int* dst = ei + E;

    const int nB = (N + BNODES - 1) >> BSHIFT;   // 196

    auto align1k = [](size_t v) { return (v + 1023) & ~(size_t)1023; };
    char* p = (char*)d_ws;
    int*      gCursor = (int*)p;        p += align1k(256 * 4);
    float*    dinv    = (float*)p;      p += align1k((size_t)N * 4);
    int*      beg     = (int*)p;        p += align1k((size_t)N * 4);
    int*      endp    = (int*)p;        p += align1k((size_t)N * 4);
    unsigned* pairs   = (unsigned*)p;   p += align1k((size_t)nB * BCAP * 4);
    bf16_t*   H1      = (bf16_t*)p;     p += align1k((size_t)N * FDIM * 2);
    bf16_t*   H2      = (bf16_t*)p;     // N*64 bf16

    // ---- CSR build via bucket + LDS counting sort ----
    k_zero<<<1, 256, 0, stream>>>(gCursor);
    k_bucket<<<(E + EPB - 1) / EPB, 256, 0, stream>>>(src, dst, gCursor, pairs, E, N);
    k_sort<<<nB, 1024, 0, stream>>>(pairs, gCursor, dinv, beg, endp, N);

    const int gemmBlocks = (N + 63) / 64;
    const int aggBlocks  = (N + 15) / 16;      // 16 nodes per block (4 per wave)
    const int* srcList = (const int*)pairs;

    // ---- layer 1 GEMM ----
    k_gemm_f32<<<gemmBlocks, 256, 0, stream>>>(x, W1, dinv, H1, N);
    // ---- fused layer-1 aggregate + layer-2 GEMM ----
    k_aggemm<<<gemmBlocks, 256, 0, stream>>>(H1, srcList, beg, endp, dinv, b1, W2, H2, N);
    // ---- layer-2 aggregate -> output ----
    k_agg<<<aggBlocks, 256, 0, stream>>>(H2, srcList, beg, endp, dinv, b2, out, N);
}

// Round 9
// 174.815 us; speedup vs baseline: 8.8069x; 1.0035x over previous
//
#include <hip/hip_runtime.h>

#define FDIM   64
#define BSHIFT 9            // 512 nodes per bucket
#define BNODES 512
#define BCAP   8960         // slots per bucket (mean 8163, sd ~90 -> +8.8 sigma)
#define EPB    4096         // edges per k_bucket block

typedef unsigned short bf16_t;

__device__ __forceinline__ float bflo(unsigned u) { return __uint_as_float(u << 16); }
__device__ __forceinline__ float bfhi(unsigned u) { return __uint_as_float(u & 0xFFFF0000u); }
__device__ __forceinline__ unsigned f2bf(float f) {   // RNE, returns low 16 bits
    unsigned u = __float_as_uint(f);
    u += 0x7FFFu + ((u >> 16) & 1u);
    return u >> 16;
}
__device__ __forceinline__ void addbf8(float* acc, uint4 v) {
    acc[0] += bflo(v.x); acc[1] += bfhi(v.x);
    acc[2] += bflo(v.y); acc[3] += bfhi(v.y);
    acc[4] += bflo(v.z); acc[5] += bfhi(v.z);
    acc[6] += bflo(v.w); acc[7] += bfhi(v.w);
}

// ---------------- zero the 256-int global cursor ----------------
__global__ void k_zero(int* __restrict__ g) { g[threadIdx.x] = 0; }

// ---------------- pass A: bucket edges by dst, pack (localDst<<17 | src) ----------------
// per-WAVE histogram + cursor copies: no cross-wave same-address LDS atomics.
__global__ __launch_bounds__(256) void k_bucket(const int* __restrict__ src,
                                                const int* __restrict__ dst,
                                                int* __restrict__ gCursor,
                                                unsigned* __restrict__ pairs,
                                                int E, int N) {
    __shared__ int cnt4[4][256];
    __shared__ int cur4[4][256];
    const int t  = threadIdx.x;
    const int w  = t >> 6;
    const int e0 = blockIdx.x * EPB;
    int dcache[EPB / 256];
    #pragma unroll
    for (int i = 0; i < 4; ++i) cnt4[i][t] = 0;
    __syncthreads();

    // phase 1: per-wave count, cache clamped dst
    #pragma unroll 4
    for (int i = 0; i < EPB / 256; ++i) {
        int e = e0 + i * 256 + t;
        int d = -1;
        if (e < E) {
            d = dst[e];
            d = min(max(d, 0), N - 1);
            atomicAdd(&cnt4[w][d >> BSHIFT], 1);
        }
        dcache[i] = d;
    }
    __syncthreads();
    // phase 2: merge, reserve global range, set per-wave cursors
    {
        int c0 = cnt4[0][t], c1 = cnt4[1][t], c2 = cnt4[2][t], c3 = cnt4[3][t];
        int tot = c0 + c1 + c2 + c3;
        int b = 0;
        if (tot > 0) b = atomicAdd(&gCursor[t], tot);
        cur4[0][t] = b;
        cur4[1][t] = b + c0;
        cur4[2][t] = b + c0 + c1;
        cur4[3][t] = b + c0 + c1 + c2;
    }
    __syncthreads();
    // phase 3: write packed pairs via per-wave cursors
    #pragma unroll 4
    for (int i = 0; i < EPB / 256; ++i) {
        int d = dcache[i];
        if (d >= 0) {
            int e = e0 + i * 256 + t;
            int s = src[e];
            s = min(max(s, 0), N - 1);
            int bk = d >> BSHIFT;
            int slot = atomicAdd(&cur4[w][bk], 1);
            if (slot < BCAP)
                pairs[(size_t)bk * BCAP + slot] =
                    ((unsigned)(d & (BNODES - 1)) << 17) | (unsigned)s;
        }
    }
}

// ---------------- pass B: per-bucket counting sort (in LDS), in-place scatter ----------------
// 4 groups of 4 waves, each with private histogram/cursor copy (contention /4).
__global__ __launch_bounds__(1024) void k_sort(unsigned* __restrict__ pairs,
                                               const int* __restrict__ gCursor,
                                               float* __restrict__ dinv,
                                               int* __restrict__ beg,
                                               int* __restrict__ endp,
                                               int N) {
    __shared__ unsigned buf[BCAP];      // 35 KB
    __shared__ int cnt4[4][BNODES];     // 8 KB
    __shared__ int scn[BNODES];         // 2 KB
    __shared__ int cur4[4][BNODES];     // 8 KB
    const int b = blockIdx.x, t = threadIdx.x;
    const int grp = t >> 8;             // 0..3 (4 waves per group)
    const int count = min(gCursor[b], BCAP);
    unsigned* p = pairs + (size_t)b * BCAP;

    ((int*)cnt4)[t] = 0;
    ((int*)cnt4)[t + 1024] = 0;
    __syncthreads();
    // stage to LDS + per-group histogram
    for (int i = t; i < count; i += 1024) {
        unsigned pk = p[i];
        buf[i] = pk;
        atomicAdd(&cnt4[grp][pk >> 17], 1);
    }
    __syncthreads();
    if (t < BNODES) scn[t] = cnt4[0][t] + cnt4[1][t] + cnt4[2][t] + cnt4[3][t];
    __syncthreads();
    for (int off = 1; off < BNODES; off <<= 1) {
        int v = 0;
        if (t < BNODES && t >= off) v = scn[t - off];
        __syncthreads();
        if (t < BNODES) scn[t] += v;
        __syncthreads();
    }
    if (t < BNODES) {
        int c0 = cnt4[0][t], c1 = cnt4[1][t], c2 = cnt4[2][t], c3 = cnt4[3][t];
        int tot = c0 + c1 + c2 + c3;
        int st  = scn[t] - tot;         // exclusive
        cur4[0][t] = st;
        cur4[1][t] = st + c0;
        cur4[2][t] = st + c0 + c1;
        cur4[3][t] = st + c0 + c1 + c2;
        int n = (b << BSHIFT) + t;
        if (n < N) {
            beg[n]  = b * BCAP + st;
            endp[n] = b * BCAP + st + tot;
            dinv[n] = rsqrtf((float)(tot + 1));
        }
    }
    __syncthreads();
    // scatter back (source is LDS, per-group cursors)
    for (int i = t; i < count; i += 1024) {
        unsigned pk = buf[i];
        int pos = atomicAdd(&cur4[grp][pk >> 17], 1);
        p[pos] = pk & 0x1FFFFu;
    }
}

// ---------------- GEMM (fp32 in): Ob[r] = bf16( dinv[r] * (X @ W)[r] ) ----------------
__global__ __launch_bounds__(256) void k_gemm_f32(const float* __restrict__ X,
                                                  const float* __restrict__ W,
                                                  const float* __restrict__ dinv,
                                                  bf16_t* __restrict__ Ob, int N) {
    __shared__ float Xs[64][FDIM];
    __shared__ float Ws[64][FDIM];
    const int tid  = threadIdx.x;
    const int base = blockIdx.x * 64;

    #pragma unroll
    for (int i = 0; i < 4; ++i) {
        int idx = tid + i * 256;
        reinterpret_cast<float4*>(&Ws[0][0])[idx] =
            reinterpret_cast<const float4*>(W)[idx];
    }
    #pragma unroll
    for (int i = 0; i < 4; ++i) {
        int idx = tid + i * 256;
        int r = idx >> 4;
        int gr = base + r;
        float4 v = make_float4(0.f, 0.f, 0.f, 0.f);
        if (gr < N) v = reinterpret_cast<const float4*>(X)[(size_t)gr * 16 + (idx & 15)];
        reinterpret_cast<float4*>(&Xs[0][0])[idx] = v;
    }
    __syncthreads();

    const int c  = tid & 63;
    const int rq = tid >> 6;
    float acc[16];
    #pragma unroll
    for (int j = 0; j < 16; ++j) acc[j] = 0.f;

    #pragma unroll 8
    for (int k = 0; k < 64; ++k) {
        float wv = Ws[k][c];
        #pragma unroll
        for (int j = 0; j < 16; ++j)
            acc[j] = fmaf(Xs[rq * 16 + j][k], wv, acc[j]);
    }

    #pragma unroll
    for (int j = 0; j < 16; ++j) {
        int gr = base + rq * 16 + j;
        if (gr < N) Ob[(size_t)gr * FDIM + c] = (bf16_t)f2bf(acc[j] * dinv[gr]);
    }
}

// ---------------- GEMM (bf16 in): Ob[r] = bf16( dinv[r] * (Y @ W)[r] ) ----------------
__global__ __launch_bounds__(256) void k_gemm_bf16(const bf16_t* __restrict__ Y,
                                                   const float* __restrict__ W,
                                                   const float* __restrict__ dinv,
                                                   bf16_t* __restrict__ Ob, int N) {
    __shared__ float Xs[64][FDIM];
    __shared__ float Ws[64][FDIM];
    const int tid  = threadIdx.x;
    const int base = blockIdx.x * 64;

    #pragma unroll
    for (int i = 0; i < 4; ++i) {
        int idx = tid + i * 256;
        reinterpret_cast<float4*>(&Ws[0][0])[idx] =
            reinterpret_cast<const float4*>(W)[idx];
    }
    #pragma unroll
    for (int i = 0; i < 2; ++i) {
        int idx = tid + i * 256;
        int r = idx >> 3, ci = idx & 7;
        int gr = base + r;
        uint4 v = make_uint4(0u, 0u, 0u, 0u);
        if (gr < N) v = reinterpret_cast<const uint4*>(Y)[(size_t)gr * 8 + ci];
        float* xp = &Xs[r][ci * 8];
        xp[0] = bflo(v.x); xp[1] = bfhi(v.x);
        xp[2] = bflo(v.y); xp[3] = bfhi(v.y);
        xp[4] = bflo(v.z); xp[5] = bfhi(v.z);
        xp[6] = bflo(v.w); xp[7] = bfhi(v.w);
    }
    __syncthreads();

    const int c  = tid & 63;
    const int rq = tid >> 6;
    float acc[16];
    #pragma unroll
    for (int j = 0; j < 16; ++j) acc[j] = 0.f;

    #pragma unroll 8
    for (int k = 0; k < 64; ++k) {
        float wv = Ws[k][c];
        #pragma unroll
        for (int j = 0; j < 16; ++j)
            acc[j] = fmaf(Xs[rq * 16 + j][k], wv, acc[j]);
    }

    #pragma unroll
    for (int j = 0; j < 16; ++j) {
        int gr = base + rq * 16 + j;
        if (gr < N) Ob[(size_t)gr * FDIM + c] = (bf16_t)f2bf(acc[j] * dinv[gr]);
    }
}

// ---------------- CSR gather-aggregate (bf16 rows), 4 nodes per wave ----------------
// 8 groups of 8 lanes = 4 nodes x 2 edge-slots; direct srcList load (same-address
// broadcast), 4 outstanding 128B gathers per group, one shfl_xor(8) merge.
__global__ __launch_bounds__(256) void k_agg(const bf16_t* __restrict__ Hs,
                                             const int* __restrict__ srcList,
                                             const int* __restrict__ beg,
                                             const int* __restrict__ endp,
                                             const float* __restrict__ dinv,
                                             const float* __restrict__ bias,
                                             float* __restrict__ Of,
                                             bf16_t* __restrict__ Ob,
                                             int N, int do_relu) {
    const int lane = threadIdx.x & 63;
    const int w    = threadIdx.x >> 6;        // wave 0..3
    const int g    = lane >> 3;               // group 0..7
    const int c8   = lane & 7;                // uint4 chunk of row
    const int nl   = g >> 1;                  // node-in-wave 0..3
    const int par  = g & 1;                   // edge-slot parity
    const int node = (blockIdx.x * 4 + w) * 4 + nl;

    const uint4* Hv = reinterpret_cast<const uint4*>(Hs) + c8;

    int kb = 0, ke = 0;
    if (node < N) { kb = beg[node]; ke = endp[node]; }

    float acc[8];
    #pragma unroll
    for (int i = 0; i < 8; ++i) acc[i] = 0.f;

    int k = kb + par;
    for (; k + 6 < ke; k += 8) {          // 4 outstanding gather chains
        int s0 = srcList[k],     s1 = srcList[k + 2];
        int s2 = srcList[k + 4], s3 = srcList[k + 6];
        uint4 h0 = Hv[(size_t)s0 * 8];
        uint4 h1 = Hv[(size_t)s1 * 8];
        uint4 h2 = Hv[(size_t)s2 * 8];
        uint4 h3 = Hv[(size_t)s3 * 8];
        addbf8(acc, h0); addbf8(acc, h1); addbf8(acc, h2); addbf8(acc, h3);
    }
    for (; k < ke; k += 2) {
        uint4 h0 = Hv[(size_t)srcList[k] * 8];
        addbf8(acc, h0);
    }

    // merge the two edge-slots of this node
    #pragma unroll
    for (int i = 0; i < 8; ++i) acc[i] += __shfl_xor(acc[i], 8, 64);

    if (node >= N || par != 0) return;

    // self-loop term
    uint4 sv = Hv[(size_t)node * 8];
    addbf8(acc, sv);

    const float di = dinv[node];
    const float4* bv = reinterpret_cast<const float4*>(bias);
    float4 b0 = bv[c8 * 2], b1 = bv[c8 * 2 + 1];
    float r[8];
    r[0] = fmaf(di, acc[0], b0.x); r[1] = fmaf(di, acc[1], b0.y);
    r[2] = fmaf(di, acc[2], b0.z); r[3] = fmaf(di, acc[3], b0.w);
    r[4] = fmaf(di, acc[4], b1.x); r[5] = fmaf(di, acc[5], b1.y);
    r[6] = fmaf(di, acc[6], b1.z); r[7] = fmaf(di, acc[7], b1.w);
    if (do_relu) {
        #pragma unroll
        for (int i = 0; i < 8; ++i) r[i] = fmaxf(r[i], 0.f);
    }
    if (Ob) {
        uint4 o;
        o.x = f2bf(r[0]) | (f2bf(r[1]) << 16);
        o.y = f2bf(r[2]) | (f2bf(r[3]) << 16);
        o.z = f2bf(r[4]) | (f2bf(r[5]) << 16);
        o.w = f2bf(r[6]) | (f2bf(r[7]) << 16);
        reinterpret_cast<uint4*>(Ob)[(size_t)node * 8 + c8] = o;
    } else {
        float4 o0 = make_float4(r[0], r[1], r[2], r[3]);
        float4 o1 = make_float4(r[4], r[5], r[6], r[7]);
        reinterpret_cast<float4*>(Of)[(size_t)node * 16 + c8 * 2]     = o0;
        reinterpret_cast<float4*>(Of)[(size_t)node * 16 + c8 * 2 + 1] = o1;
    }
}

extern "C" void kernel_launch(void* const* d_in, const int* in_sizes, int n_in,
                              void* d_out, int out_size, void* d_ws, size_t ws_size,
                              hipStream_t stream) {
    const float* x  = (const float*)d_in[0];
    const int*   ei = (const int*)  d_in[1];   // [2, E], int32
    const float* W1 = (const float*)d_in[2];
    const float* b1 = (const float*)d_in[3];
    const float* W2 = (const float*)d_in[4];
    const float* b2 = (const float*)d_in[5];
    float* out = (float*)d_out;

    const int N = in_sizes[0] / FDIM;   // 100000
    const int E = in_sizes[1] / 2;      // 1600000
    const int* src = ei;
    const int* dst = ei + E;

    const int nB = (N + BNODES - 1) >> BSHIFT;   // 196

    auto align1k = [](size_t v) { return (v + 1023) & ~(size_t)1023; };
    char* p = (char*)d_ws;
    int*      gCursor = (int*)p;        p += align1k(256 * 4);
    float*    dinv    = (float*)p;      p += align1k((size_t)N * 4);
    int*      beg     = (int*)p;        p += align1k((size_t)N * 4);
    int*      endp    = (int*)p;        p += align1k((size_t)N * 4);
    unsigned* pairs   = (unsigned*)p;   p += align1k((size_t)nB * BCAP * 4);
    bf16_t*   H       = (bf16_t*)p;     p += align1k((size_t)N * FDIM * 2);
    bf16_t*   Y       = (bf16_t*)p;     // N*64 bf16 (layer-1 activations)

    // ---- CSR build via bucket + LDS counting sort ----
    k_zero<<<1, 256, 0, stream>>>(gCursor);
    k_bucket<<<(E + EPB - 1) / EPB, 256, 0, stream>>>(src, dst, gCursor, pairs, E, N);
    k_sort<<<nB, 1024, 0, stream>>>(pairs, gCursor, dinv, beg, endp, N);

    const int gemmBlocks = (N + 63) / 64;
    const int aggBlocks  = (N + 15) / 16;      // 16 nodes per block (4 per wave)
    const int* srcList = (const int*)pairs;

    // ---- layer 1 ----
    k_gemm_f32<<<gemmBlocks, 256, 0, stream>>>(x, W1, dinv, H, N);
    k_agg<<<aggBlocks, 256, 0, stream>>>(H, srcList, beg, endp, dinv, b1,
                                         nullptr, Y, N, 1);

    // ---- layer 2 ----
    k_gemm_bf16<<<gemmBlocks, 256, 0, stream>>>(Y, W2, dinv, H, N);
    k_agg<<<aggBlocks, 256, 0, stream>>>(H, srcList, beg, endp, dinv, b2,
                                         out, nullptr, N, 0);
}